// Round 1
// baseline (274.973 us; speedup 1.0000x reference)
//
#include <hip/hip_runtime.h>
#include <hip/hip_bf16.h>

// Problem constants
#define Bb   2
#define Nn   512
#define Cc   384
#define Hh   12
#define Pp   4
#define DPp  128
#define CHh  32
#define BN   1024          // B*N
#define NC1  1584          // 3*384 + 3*144 concatenated proj cols
#define CT1  99            // 1584/16 col-tiles
#define SCALE 0.17677669529663687f   // 32^-0.5

typedef __attribute__((ext_vector_type(8))) short short8;
typedef __attribute__((ext_vector_type(4))) float f32x4;

__device__ __forceinline__ unsigned short f2bf(float f){
  union { float f; unsigned u; } v; v.f = f;
  unsigned u = v.u;
  unsigned r = u + 0x7fffu + ((u >> 16) & 1u);
  return (unsigned short)(r >> 16);
}
__device__ __forceinline__ float bf_lo(unsigned u){ union{unsigned u; float f;} v; v.u = u << 16; return v.f; }
__device__ __forceinline__ float bf_hi(unsigned u){ union{unsigned u; float f;} v; v.u = u & 0xffff0000u; return v.f; }
__device__ __forceinline__ unsigned pack2(float a, float b){
  return (unsigned)f2bf(a) | ((unsigned)f2bf(b) << 16);
}

// ---------------------------------------------------------------- prep kernel
struct PrepArgs {
  const float *single, *Wq, *Wk, *Wv, *Wqp, *Wkp, *Wvp, *Wpo, *Wo;
  const float *bq, *bk, *bv, *bqp, *bkp, *bvp;
  unsigned short *sbf, *wcat, *wpof, *wof, *wppad;
  float *bcat;
};

__global__ void prep_kernel(PrepArgs pa){
  const int n0 = BN * Cc;            // single -> bf16
  const int n1 = 12 * CT1 * 512;     // wcat frag elems (608256)
  const int n2 = 5 * 24 * 512;       // wpo frag (61440), K padded 144->160
  const int n3 = 12 * 24 * 512;      // wo frag (147456)
  const int n4 = NC1;                // concat bias
  const int n5 = BN * 16;            // zero pad cols 144..159 of wp buffer
  const int total = n0 + n1 + n2 + n3 + n4 + n5;
  for (int i = blockIdx.x * blockDim.x + threadIdx.x; i < total; i += gridDim.x * blockDim.x){
    int e = i;
    if (e < n0){ pa.sbf[e] = f2bf(pa.single[e]); continue; }
    e -= n0;
    if (e < n1){
      int j8 = e & 7, l = (e >> 3) & 63, ctt = e >> 9;
      int ct = ctt % CT1, t = ctt / CT1;
      int k = t * 32 + ((l >> 4) << 3) + j8;
      int col = (ct << 4) + (l & 15);
      float v;
      if (col < 1152){
        const float* W = (col < 384) ? pa.Wq : (col < 768 ? pa.Wk : pa.Wv);
        v = W[k * 384 + (col % 384)];
      } else {
        int c2 = col - 1152;
        const float* W = (c2 < 144) ? pa.Wqp : (c2 < 288 ? pa.Wkp : pa.Wvp);
        v = W[k * 144 + (c2 % 144)];
      }
      pa.wcat[e] = f2bf(v); continue;
    }
    e -= n1;
    if (e < n2){
      int j8 = e & 7, l = (e >> 3) & 63, ctt = e >> 9;
      int ct = ctt % 24, t = ctt / 24;
      int k = t * 32 + ((l >> 4) << 3) + j8;
      int col = (ct << 4) + (l & 15);
      pa.wpof[e] = (k < 144) ? f2bf(pa.Wpo[k * 384 + col]) : (unsigned short)0;
      continue;
    }
    e -= n2;
    if (e < n3){
      int j8 = e & 7, l = (e >> 3) & 63, ctt = e >> 9;
      int ct = ctt % 24, t = ctt / 24;
      int k = t * 32 + ((l >> 4) << 3) + j8;
      int col = (ct << 4) + (l & 15);
      pa.wof[e] = f2bf(pa.Wo[k * 384 + col]);
      continue;
    }
    e -= n3;
    if (e < n4){
      int col = e; float v;
      if (col < 1152){
        const float* bb = (col < 384) ? pa.bq : (col < 768 ? pa.bk : pa.bv);
        v = bb[col % 384];
      } else {
        int c2 = col - 1152;
        const float* bb = (c2 < 144) ? pa.bqp : (c2 < 288 ? pa.bkp : pa.bvp);
        v = bb[c2 % 144];
      }
      pa.bcat[col] = v; continue;
    }
    e -= n4;
    { int row = e >> 4, c = e & 15; pa.wppad[row * 160 + 144 + c] = 0; }
  }
}

// ------------------------------------------------------------ generic MFMA GEMM
// C[M][ncols] = A[M][lda](bf16) @ Wfrag + bias (+addend). 64x48 tile per block.
__global__ __launch_bounds__(256) void gemm_mfma(
    const unsigned short* __restrict__ A, int lda, int ksteps,
    const unsigned short* __restrict__ wfrag, int ct_total,
    const float* __restrict__ bias, const float* __restrict__ addend,
    float* __restrict__ outf, unsigned short* __restrict__ outb, int ncols)
{
  int l = threadIdx.x & 63, w = threadIdx.x >> 6;
  int m0 = blockIdx.x * 64 + w * 16;
  const unsigned short* Ap = A + (long)(m0 + (l & 15)) * lda + ((l >> 4) << 3);
  int ct0 = blockIdx.y * 3;
  f32x4 acc0 = {0,0,0,0}, acc1 = {0,0,0,0}, acc2 = {0,0,0,0};
  for (int t = 0; t < ksteps; ++t){
    short8 a = *(const short8*)(Ap + t * 32);
    const unsigned short* wp_ = wfrag + ((long)(t * ct_total + ct0) * 64 + l) * 8;
    short8 b0 = *(const short8*)(wp_);
    short8 b1 = *(const short8*)(wp_ + 512);
    short8 b2 = *(const short8*)(wp_ + 1024);
    acc0 = __builtin_amdgcn_mfma_f32_16x16x32_bf16(a, b0, acc0, 0, 0, 0);
    acc1 = __builtin_amdgcn_mfma_f32_16x16x32_bf16(a, b1, acc1, 0, 0, 0);
    acc2 = __builtin_amdgcn_mfma_f32_16x16x32_bf16(a, b2, acc2, 0, 0, 0);
  }
  int rbase = m0 + ((l >> 4) << 2);
  int cb = blockIdx.y * 48 + (l & 15);
#pragma unroll
  for (int c = 0; c < 3; ++c){
    f32x4 ac = (c == 0) ? acc0 : (c == 1 ? acc1 : acc2);
    int col = cb + c * 16;
    float bb = bias[col];
#pragma unroll
    for (int r = 0; r < 4; ++r){
      long idx = (long)(rbase + r) * ncols + col;
      float v = ac[r] + bb;
      if (addend) v += addend[idx];
      if (outb) outb[idx] = f2bf(v); else outf[idx] = v;
    }
  }
}

// ------------------------------------------------------- pair bias (the 268MB)
__global__ __launch_bounds__(256) void bias_kernel(
    const float* __restrict__ pair, const float* __restrict__ Wpb,
    const float* __restrict__ bpb, float* __restrict__ biasout)
{
  int l = threadIdx.x & 63, w = threadIdx.x >> 6;
  long m0 = (long)blockIdx.x * 64 + w * 16;
  long m = m0 + (l & 15);
  int kb = (l >> 4) << 3;
  int col = l & 15;
  short8 bf[4];
#pragma unroll
  for (int t = 0; t < 4; ++t){
#pragma unroll
    for (int j = 0; j < 8; ++j){
      int k = t * 32 + kb + j;
      float v = (col < 12) ? Wpb[k * 12 + col] : 0.f;
      bf[t][j] = (short)f2bf(v);
    }
  }
  const float* pr = pair + m * 128 + kb;
  f32x4 acc = {0,0,0,0};
#pragma unroll
  for (int t = 0; t < 4; ++t){
    float4 x0 = *(const float4*)(pr + t * 32);
    float4 x1 = *(const float4*)(pr + t * 32 + 4);
    short8 a;
    a[0] = (short)f2bf(x0.x); a[1] = (short)f2bf(x0.y);
    a[2] = (short)f2bf(x0.z); a[3] = (short)f2bf(x0.w);
    a[4] = (short)f2bf(x1.x); a[5] = (short)f2bf(x1.y);
    a[6] = (short)f2bf(x1.z); a[7] = (short)f2bf(x1.w);
    acc = __builtin_amdgcn_mfma_f32_16x16x32_bf16(a, bf[t], acc, 0, 0, 0);
  }
  int h = col;
  if (h < 12){
    long mr = m0 + ((l >> 4) << 2);
    long jj = mr & 511, ii = (mr >> 9) & 511, b = mr >> 18;
    float bb = bpb[h];
    float4 o; o.x = acc[0] + bb; o.y = acc[1] + bb; o.z = acc[2] + bb; o.w = acc[3] + bb;
    *(float4*)(biasout + (((b * 12 + h) * 512 + ii) * 512 + jj)) = o;
  }
}

// --------------------------------------------- local->global frame + sq norms
__global__ void transform_kernel(
    const float* __restrict__ proj, const float* __restrict__ rot,
    const float* __restrict__ trans, float* __restrict__ qg, float* __restrict__ kg,
    float* __restrict__ vg, float* __restrict__ q2, float* __restrict__ k2)
{
  int tid = blockIdx.x * blockDim.x + threadIdx.x;
  if (tid >= 3 * BN * Hh) return;
  int a = tid / (BN * Hh); int r = tid % (BN * Hh); int bn = r / Hh; int h = r % Hh;
  const float* R = rot + bn * 9;
  const float* T = trans + bn * 3;
  const float* src = proj + (long)bn * NC1 + 1152 + a * 144 + h * 12;
  float* dst = ((a == 0) ? qg : (a == 1) ? kg : vg) + bn * 144 + h * 12;
  float s2 = 0.f;
#pragma unroll
  for (int p = 0; p < 4; ++p){
    float d0 = src[p * 3], d1 = src[p * 3 + 1], d2 = src[p * 3 + 2];
#pragma unroll
    for (int e = 0; e < 3; ++e){
      float g = d0 * R[e] + d1 * R[3 + e] + d2 * R[6 + e] + T[e];
      dst[p * 3 + e] = g; s2 += g * g;
    }
  }
  if (a == 0) q2[bn * 12 + h] = s2;
  else if (a == 1) k2[bn * 12 + h] = s2;
}

// -------------------------------------------------------------- attention core
__global__ __launch_bounds__(256) void attn_kernel(
    const float* __restrict__ proj, const float* __restrict__ qg,
    const float* __restrict__ kg, const float* __restrict__ vg,
    const float* __restrict__ q2, const float* __restrict__ k2,
    const float* __restrict__ biasb, const float* __restrict__ mask,
    float* __restrict__ wsout, unsigned short* __restrict__ wpout)
{
  __shared__ unsigned int kpk[22][258];   // packed bf16 pairs: K (or V) tile, half of j
  __shared__ float logits[16][513];
  __shared__ unsigned int qpk[22][16];
  __shared__ float q2s[16], mski[16], k2s[512], mskj[512];

  int i0 = blockIdx.x * 16; int h = blockIdx.y; int b = blockIdx.z;
  int t = threadIdx.x;

  { // stage q-side
    int qi = t >> 4, cp = t & 15;
    long bn = (long)b * Nn + i0 + qi;
    const float* qp_ = proj + bn * NC1 + h * 32 + cp * 2;
    qpk[cp][qi] = pack2(qp_[0], qp_[1]);
    if (cp < 6){
      const float* g = qg + bn * 144 + h * 12 + cp * 2;
      qpk[16 + cp][qi] = pack2(g[0], g[1]);
    }
    if (cp == 6) q2s[qi] = q2[bn * 12 + h];
    if (cp == 7) mski[qi] = mask[b * Nn + i0 + qi];
  }
  __syncthreads();

  // ---- phase 1: logits, j in two halves of 256
  for (int half = 0; half < 2; ++half){
    int j0 = half * 256;
    __syncthreads();
    { // stage K half-tile: 8 threads per j (coalesced 128B runs)
      int jg = t >> 3, s = t & 7;
      for (int pass = 0; pass < 8; ++pass){
        int j = jg + pass * 32;
        long bnj = (long)b * Nn + j0 + j;
        const float* kp_ = proj + bnj * NC1 + 384 + h * 32 + s * 4;
        float4 kv = *(const float4*)kp_;
        kpk[s * 2][j]     = pack2(kv.x, kv.y);
        kpk[s * 2 + 1][j] = pack2(kv.z, kv.w);
        if (s < 3){
          const float* g = kg + bnj * 144 + h * 12 + s * 4;
          float4 gv = *(const float4*)g;
          kpk[16 + s * 2][j]     = pack2(gv.x, gv.y);
          kpk[16 + s * 2 + 1][j] = pack2(gv.z, gv.w);
        }
        if (s == 3) k2s[j0 + j] = k2[bnj * 12 + h];
        if (s == 4) mskj[j0 + j] = mask[b * Nn + j0 + j];
      }
    }
    __syncthreads();
    {
      int j = t & 255;
      int jj = j0 + j;
      unsigned kreg[22];
#pragma unroll
      for (int r = 0; r < 22; ++r) kreg[r] = kpk[r][j];
      float k2j = k2s[jj]; float mj = mskj[jj];
      const float* bptr = biasb + (((long)(b * 12 + h) * Nn + i0) * Nn) + jj;
#pragma unroll 4
      for (int qi = 0; qi < 16; ++qi){
        float dot = 0.f;
#pragma unroll
        for (int r = 0; r < 22; ++r){
          unsigned qu = qpk[r][qi]; unsigned ku = kreg[r];
          dot = fmaf(bf_lo(qu), bf_lo(ku), dot);
          dot = fmaf(bf_hi(qu), bf_hi(ku), dot);
        }
        float lg = bptr[(long)qi * Nn] + SCALE * dot - 0.5f * SCALE * (q2s[qi] + k2j);
        if (mski[qi] * mj == 0.f) lg = -1e9f;
        logits[qi][jj] = lg;
      }
    }
  }
  __syncthreads();

  // ---- softmax (one wave per 4 rows)
  {
    int wv = t >> 6, ln = t & 63;
    for (int qi = wv; qi < 16; qi += 4){
      float m = -3.4e38f;
      for (int x = ln; x < 512; x += 64) m = fmaxf(m, logits[qi][x]);
      for (int off = 32; off; off >>= 1) m = fmaxf(m, __shfl_xor(m, off));
      float s = 0.f;
      for (int x = ln; x < 512; x += 64){
        float p = __expf(logits[qi][x] - m);
        logits[qi][x] = p; s += p;
      }
      for (int off = 32; off; off >>= 1) s += __shfl_xor(s, off);
      float inv = 1.f / s;
      for (int x = ln; x < 512; x += 64) logits[qi][x] *= inv;
    }
  }
  __syncthreads();

  // ---- phase 3: attn @ [v | vg]  (44 output cols, 3 per thread group)
  float acc3[3] = {0.f, 0.f, 0.f};
  int qi3 = t >> 4, g3 = t & 15;
  for (int half = 0; half < 2; ++half){
    int j0 = half * 256;
    __syncthreads();
    { // stage V half-tile into kpk
      int jg = t >> 3, s = t & 7;
      for (int pass = 0; pass < 8; ++pass){
        int j = jg + pass * 32;
        long bnj = (long)b * Nn + j0 + j;
        const float* vp_ = proj + bnj * NC1 + 768 + h * 32 + s * 4;
        float4 vv = *(const float4*)vp_;
        kpk[s * 2][j]     = pack2(vv.x, vv.y);
        kpk[s * 2 + 1][j] = pack2(vv.z, vv.w);
        if (s < 3){
          const float* g = vg + bnj * 144 + h * 12 + s * 4;
          float4 gv = *(const float4*)g;
          kpk[16 + s * 2][j]     = pack2(gv.x, gv.y);
          kpk[16 + s * 2 + 1][j] = pack2(gv.z, gv.w);
        }
      }
    }
    __syncthreads();
    if (g3 * 3 < 44){
      for (int j = 0; j < 256; ++j){
        float a_ = logits[qi3][j0 + j];
#pragma unroll
        for (int c = 0; c < 3; ++c){
          int col = g3 * 3 + c;
          if (col < 44){
            unsigned vu = kpk[col >> 1][j];
            float vv = (col & 1) ? bf_hi(vu) : bf_lo(vu);
            acc3[c] = fmaf(a_, vv, acc3[c]);
          }
        }
      }
    }
  }
  { // write
    long bn = (long)b * Nn + i0 + qi3;
#pragma unroll
    for (int c = 0; c < 3; ++c){
      int col = g3 * 3 + c;
      if (col < 32) wsout[bn * 384 + h * 32 + col] = acc3[c];
      else if (col < 44) wpout[bn * 160 + h * 12 + (col - 32)] = f2bf(acc3[c]);
    }
  }
}

// ---------------------------------------------------------------- layer norm
__global__ __launch_bounds__(256) void ln_kernel(
    const float* __restrict__ x, const float* __restrict__ g,
    const float* __restrict__ bta, float* __restrict__ out)
{
  int wv = threadIdx.x >> 6, ln = threadIdx.x & 63;
  long row = (long)blockIdx.x * 4 + wv;
  const float* xr = x + row * 384;
  float v[6]; float s = 0.f, s2 = 0.f;
#pragma unroll
  for (int i = 0; i < 6; ++i){
    v[i] = xr[ln + i * 64]; s += v[i]; s2 += v[i] * v[i];
  }
  for (int off = 32; off; off >>= 1){ s += __shfl_xor(s, off); s2 += __shfl_xor(s2, off); }
  float mu = s * (1.f / 384.f);
  float var = s2 * (1.f / 384.f) - mu * mu;
  float inv = rsqrtf(var + 1e-5f);
  float* orow = out + row * 384;
#pragma unroll
  for (int i = 0; i < 6; ++i){
    int c = ln + i * 64;
    orow[c] = (v[i] - mu) * inv * g[c] + bta[c];
  }
}

// -------------------------------------------------------------------- launcher
extern "C" void kernel_launch(void* const* d_in, const int* in_sizes, int n_in,
                              void* d_out, int out_size, void* d_ws, size_t ws_size,
                              hipStream_t stream)
{
  const float* single = (const float*)d_in[0];
  const float* pair   = (const float*)d_in[1];
  const float* rot    = (const float*)d_in[2];
  const float* trans  = (const float*)d_in[3];
  const float* mask   = (const float*)d_in[4];
  const float* Wq  = (const float*)d_in[5];  const float* bq  = (const float*)d_in[6];
  const float* Wk  = (const float*)d_in[7];  const float* bk  = (const float*)d_in[8];
  const float* Wv  = (const float*)d_in[9];  const float* bv  = (const float*)d_in[10];
  const float* Wpb = (const float*)d_in[11]; const float* bpb = (const float*)d_in[12];
  const float* Wqp = (const float*)d_in[13]; const float* bqp = (const float*)d_in[14];
  const float* Wkp = (const float*)d_in[15]; const float* bkp = (const float*)d_in[16];
  const float* Wvp = (const float*)d_in[17]; const float* bvp = (const float*)d_in[18];
  const float* Wo  = (const float*)d_in[19]; const float* bo  = (const float*)d_in[20];
  const float* Wpo = (const float*)d_in[21]; const float* bpo = (const float*)d_in[22];
  const float* ln_g = (const float*)d_in[23]; const float* ln_b = (const float*)d_in[24];

  char* wsb = (char*)d_ws;
  size_t off = 0;
  auto alloc = [&](size_t bytes) -> void* {
    void* p = wsb + off; off += (bytes + 255) & ~(size_t)255; return p;
  };
  unsigned short* sbf  = (unsigned short*)alloc((size_t)BN * Cc * 2);
  unsigned short* wcat = (unsigned short*)alloc((size_t)12 * CT1 * 512 * 2);
  unsigned short* wpof = (unsigned short*)alloc((size_t)5 * 24 * 512 * 2);
  unsigned short* wof  = (unsigned short*)alloc((size_t)12 * 24 * 512 * 2);
  float* bcat  = (float*)alloc(NC1 * 4);
  float* proj  = (float*)alloc((size_t)BN * NC1 * 4);
  float* qgb   = (float*)alloc((size_t)BN * 144 * 4);
  float* kgb   = (float*)alloc((size_t)BN * 144 * 4);
  float* vgb   = (float*)alloc((size_t)BN * 144 * 4);
  float* q2b   = (float*)alloc((size_t)BN * 12 * 4);
  float* k2b   = (float*)alloc((size_t)BN * 12 * 4);
  float* biasb = (float*)alloc((size_t)Bb * Hh * Nn * Nn * 4);
  float* wso   = (float*)alloc((size_t)BN * 384 * 4);
  unsigned short* wpbuf = (unsigned short*)alloc((size_t)BN * 160 * 2);
  unsigned short* t1    = (unsigned short*)alloc((size_t)BN * 384 * 2);
  float* xbuf  = (float*)alloc((size_t)BN * 384 * 4);
  if (off > ws_size) return;  // workspace too small: fail loudly via wrong output

  PrepArgs pa;
  pa.single = single; pa.Wq = Wq; pa.Wk = Wk; pa.Wv = Wv;
  pa.Wqp = Wqp; pa.Wkp = Wkp; pa.Wvp = Wvp; pa.Wpo = Wpo; pa.Wo = Wo;
  pa.bq = bq; pa.bk = bk; pa.bv = bv; pa.bqp = bqp; pa.bkp = bkp; pa.bvp = bvp;
  pa.sbf = sbf; pa.wcat = wcat; pa.wpof = wpof; pa.wof = wof; pa.wppad = wpbuf;
  pa.bcat = bcat;

  prep_kernel<<<512, 256, 0, stream>>>(pa);
  // projections: [1024x384] @ [384x1584]
  gemm_mfma<<<dim3(16, 33), 256, 0, stream>>>(sbf, Cc, 12, wcat, CT1, bcat,
                                              nullptr, proj, nullptr, NC1);
  transform_kernel<<<144, 256, 0, stream>>>(proj, rot, trans, qgb, kgb, vgb, q2b, k2b);
  // pair bias: [524288x128] @ [128x12] -> [B,H,N,N]
  bias_kernel<<<8192, 256, 0, stream>>>(pair, Wpb, bpb, biasb);
  attn_kernel<<<dim3(32, 12, 2), 256, 0, stream>>>(proj, qgb, kgb, vgb, q2b, k2b,
                                                   biasb, mask, wso, wpbuf);
  // t1 = wsout + wp @ Wpo + bpo  (bf16 out)
  gemm_mfma<<<dim3(16, 8), 256, 0, stream>>>(wpbuf, 160, 5, wpof, 24, bpo,
                                             wso, nullptr, t1, 384);
  // x = single + t1 @ Wo + bo  (f32 out)
  gemm_mfma<<<dim3(16, 8), 256, 0, stream>>>(t1, 384, 12, wof, 24, bo,
                                             single, xbuf, nullptr, 384);
  ln_kernel<<<256, 256, 0, stream>>>(xbuf, ln_g, ln_b, (float*)d_out);
}

// Round 2
// 133.095 us; speedup vs baseline: 2.0660x; 2.0660x over previous
//
#include <hip/hip_runtime.h>
#include <hip/hip_bf16.h>

// Problem constants
#define Bb   2
#define Nn   512
#define Cc   384
#define Hh   12
#define Pp   4
#define DPp  128
#define CHh  32
#define BN   1024          // B*N
#define NC1  1584          // 3*384 + 3*144 concatenated proj cols
#define CT1  99            // 1584/16 col-tiles
#define SCALE 0.17677669529663687f   // 32^-0.5

typedef __attribute__((ext_vector_type(8))) short short8;
typedef __attribute__((ext_vector_type(4))) float f32x4;

__device__ __forceinline__ unsigned short f2bf(float f){
  union { float f; unsigned u; } v; v.f = f;
  unsigned u = v.u;
  unsigned r = u + 0x7fffu + ((u >> 16) & 1u);
  return (unsigned short)(r >> 16);
}
__device__ __forceinline__ float bf_lo(unsigned u){ union{unsigned u; float f;} v; v.u = u << 16; return v.f; }
__device__ __forceinline__ float bf_hi(unsigned u){ union{unsigned u; float f;} v; v.u = u & 0xffff0000u; return v.f; }
__device__ __forceinline__ unsigned pack2(float a, float b){
  return (unsigned)f2bf(a) | ((unsigned)f2bf(b) << 16);
}

// ---------------------------------------------------------------- prep kernel
struct PrepArgs {
  const float *single, *Wq, *Wk, *Wv, *Wqp, *Wkp, *Wvp, *Wpo, *Wo;
  const float *bq, *bk, *bv, *bqp, *bkp, *bvp;
  unsigned short *sbf, *wcat, *wpof, *wof, *wppad;
  float *bcat;
};

__global__ void prep_kernel(PrepArgs pa){
  const int n0 = BN * Cc;            // single -> bf16
  const int n1 = 12 * CT1 * 512;     // wcat frag elems
  const int n2 = 5 * 24 * 512;       // wpo frag, K padded 144->160
  const int n3 = 12 * 24 * 512;      // wo frag
  const int n4 = NC1;                // concat bias
  const int n5 = BN * 16;            // zero pad cols 144..159 of wp buffer
  const int total = n0 + n1 + n2 + n3 + n4 + n5;
  for (int i = blockIdx.x * blockDim.x + threadIdx.x; i < total; i += gridDim.x * blockDim.x){
    int e = i;
    if (e < n0){ pa.sbf[e] = f2bf(pa.single[e]); continue; }
    e -= n0;
    if (e < n1){
      int j8 = e & 7, l = (e >> 3) & 63, ctt = e >> 9;
      int ct = ctt % CT1, t = ctt / CT1;
      int k = t * 32 + ((l >> 4) << 3) + j8;
      int col = (ct << 4) + (l & 15);
      float v;
      if (col < 1152){
        const float* W = (col < 384) ? pa.Wq : (col < 768 ? pa.Wk : pa.Wv);
        v = W[k * 384 + (col % 384)];
      } else {
        int c2 = col - 1152;
        const float* W = (c2 < 144) ? pa.Wqp : (c2 < 288 ? pa.Wkp : pa.Wvp);
        v = W[k * 144 + (c2 % 144)];
      }
      pa.wcat[e] = f2bf(v); continue;
    }
    e -= n1;
    if (e < n2){
      int j8 = e & 7, l = (e >> 3) & 63, ctt = e >> 9;
      int ct = ctt % 24, t = ctt / 24;
      int k = t * 32 + ((l >> 4) << 3) + j8;
      int col = (ct << 4) + (l & 15);
      pa.wpof[e] = (k < 144) ? f2bf(pa.Wpo[k * 384 + col]) : (unsigned short)0;
      continue;
    }
    e -= n2;
    if (e < n3){
      int j8 = e & 7, l = (e >> 3) & 63, ctt = e >> 9;
      int ct = ctt % 24, t = ctt / 24;
      int k = t * 32 + ((l >> 4) << 3) + j8;
      int col = (ct << 4) + (l & 15);
      pa.wof[e] = f2bf(pa.Wo[k * 384 + col]);
      continue;
    }
    e -= n3;
    if (e < n4){
      int col = e; float v;
      if (col < 1152){
        const float* bb = (col < 384) ? pa.bq : (col < 768 ? pa.bk : pa.bv);
        v = bb[col % 384];
      } else {
        int c2 = col - 1152;
        const float* bb = (c2 < 144) ? pa.bqp : (c2 < 288 ? pa.bkp : pa.bvp);
        v = bb[c2 % 144];
      }
      pa.bcat[col] = v; continue;
    }
    e -= n4;
    { int row = e >> 4, c = e & 15; pa.wppad[row * 160 + 144 + c] = 0; }
  }
}

// ------------------------------------------------------------ generic MFMA GEMM
__global__ __launch_bounds__(256) void gemm_mfma(
    const unsigned short* __restrict__ A, int lda, int ksteps,
    const unsigned short* __restrict__ wfrag, int ct_total,
    const float* __restrict__ bias, const float* __restrict__ addend,
    float* __restrict__ outf, unsigned short* __restrict__ outb, int ncols)
{
  int l = threadIdx.x & 63, w = threadIdx.x >> 6;
  int m0 = blockIdx.x * 64 + w * 16;
  const unsigned short* Ap = A + (long)(m0 + (l & 15)) * lda + ((l >> 4) << 3);
  int ct0 = blockIdx.y * 3;
  f32x4 acc0 = {0,0,0,0}, acc1 = {0,0,0,0}, acc2 = {0,0,0,0};
  for (int t = 0; t < ksteps; ++t){
    short8 a = *(const short8*)(Ap + t * 32);
    const unsigned short* wp_ = wfrag + ((long)(t * ct_total + ct0) * 64 + l) * 8;
    short8 b0 = *(const short8*)(wp_);
    short8 b1 = *(const short8*)(wp_ + 512);
    short8 b2 = *(const short8*)(wp_ + 1024);
    acc0 = __builtin_amdgcn_mfma_f32_16x16x32_bf16(a, b0, acc0, 0, 0, 0);
    acc1 = __builtin_amdgcn_mfma_f32_16x16x32_bf16(a, b1, acc1, 0, 0, 0);
    acc2 = __builtin_amdgcn_mfma_f32_16x16x32_bf16(a, b2, acc2, 0, 0, 0);
  }
  int rbase = m0 + ((l >> 4) << 2);
  int cb = blockIdx.y * 48 + (l & 15);
#pragma unroll
  for (int c = 0; c < 3; ++c){
    f32x4 ac = (c == 0) ? acc0 : (c == 1 ? acc1 : acc2);
    int col = cb + c * 16;
    float bb = bias[col];
#pragma unroll
    for (int r = 0; r < 4; ++r){
      long idx = (long)(rbase + r) * ncols + col;
      float v = ac[r] + bb;
      if (addend) v += addend[idx];
      if (outb) outb[idx] = f2bf(v); else outf[idx] = v;
    }
  }
}

// ---------------------- pair bias (268MB read) -> bf16 S-fragment-layout output
// biasf[b][h][jt(16)][qt(32)][f(2)][lane(64)][4] bf16
__global__ __launch_bounds__(256) void bias_kernel(
    const float* __restrict__ pair, const float* __restrict__ Wpb,
    const float* __restrict__ bpb, unsigned short* __restrict__ biasf)
{
  int l = threadIdx.x & 63, w = threadIdx.x >> 6;
  long m0 = (long)blockIdx.x * 64 + w * 16;
  long m = m0 + (l & 15);
  int kb = (l >> 4) << 3;
  int col = l & 15;
  short8 bf[4];
#pragma unroll
  for (int t = 0; t < 4; ++t){
#pragma unroll
    for (int j = 0; j < 8; ++j){
      int k = t * 32 + kb + j;
      float v = (col < 12) ? Wpb[k * 12 + col] : 0.f;
      bf[t][j] = (short)f2bf(v);
    }
  }
  const float* pr = pair + m * 128 + kb;
  f32x4 acc = {0,0,0,0};
#pragma unroll
  for (int t = 0; t < 4; ++t){
    float4 x0 = *(const float4*)(pr + t * 32);
    float4 x1 = *(const float4*)(pr + t * 32 + 4);
    short8 a;
    a[0] = (short)f2bf(x0.x); a[1] = (short)f2bf(x0.y);
    a[2] = (short)f2bf(x0.z); a[3] = (short)f2bf(x0.w);
    a[4] = (short)f2bf(x1.x); a[5] = (short)f2bf(x1.y);
    a[6] = (short)f2bf(x1.z); a[7] = (short)f2bf(x1.w);
    acc = __builtin_amdgcn_mfma_f32_16x16x32_bf16(a, bf[t], acc, 0, 0, 0);
  }
  int h = col;
  if (h < 12){
    long mr = m0 + ((l >> 4) << 2);        // first of my 4 rows; rows are consecutive j
    int b  = (int)(mr >> 18);
    int i  = (int)((mr >> 9) & 511);
    int j  = (int)(mr & 511);
    int jt = j >> 5, f = (j >> 4) & 1, g2 = (j >> 2) & 3;
    int qt = i >> 4, q = i & 15;
    float bb = bpb[h];
    long e16 = (((((long)((b * 12 + h) * 16 + jt) * 32 + qt) * 2 + f) * 64) + (g2 * 16 + q)) * 4;
    uint2 wv; wv.x = pack2(acc[0] + bb, acc[1] + bb); wv.y = pack2(acc[2] + bb, acc[3] + bb);
    *(uint2*)(biasf + e16) = wv;
  }
}

// --------------------------------------------- local->global frame + sq norms
__global__ void transform_kernel(
    const float* __restrict__ proj, const float* __restrict__ rot,
    const float* __restrict__ trans, float* __restrict__ qg, float* __restrict__ kg,
    float* __restrict__ vg, float* __restrict__ q2, float* __restrict__ k2)
{
  int tid = blockIdx.x * blockDim.x + threadIdx.x;
  if (tid >= 3 * BN * Hh) return;
  int a = tid / (BN * Hh); int r = tid % (BN * Hh); int bn = r / Hh; int h = r % Hh;
  const float* R = rot + bn * 9;
  const float* T = trans + bn * 3;
  const float* src = proj + (long)bn * NC1 + 1152 + a * 144 + h * 12;
  float* dst = ((a == 0) ? qg : (a == 1) ? kg : vg) + bn * 144 + h * 12;
  float s2 = 0.f;
#pragma unroll
  for (int p = 0; p < 4; ++p){
    float d0 = src[p * 3], d1 = src[p * 3 + 1], d2 = src[p * 3 + 2];
#pragma unroll
    for (int e = 0; e < 3; ++e){
      float g = d0 * R[e] + d1 * R[3 + e] + d2 * R[6 + e] + T[e];
      dst[p * 3 + e] = g; s2 += g * g;
    }
  }
  if (a == 0) q2[bn * 12 + h] = s2;
  else if (a == 1) k2[bn * 12 + h] = s2;
}

// --------------- pack Q/K/V into MFMA fragment-order bf16 buffers + q2h/k2h
// qf[b][h][qt(32)][ks(2)][lane(64)][8]  (A/B frag, row=lane&15, k=(lane>>4)*8+jj) * SCALE
// kf[b][h][jf(32)][ks(2)][lane(64)][8]
// vf[b][h][jt(16)][cf(3)][lane(64)][8]  (B frag, j=(lane>>4)*8+jj, col=lane&15)
// q2h/k2h[b][h][512] = -0.5*SCALE*sq + mask fold
__global__ void pack_kernel(const float* __restrict__ proj,
    const float* __restrict__ qg, const float* __restrict__ kg, const float* __restrict__ vg,
    const float* __restrict__ q2, const float* __restrict__ k2, const float* __restrict__ mask,
    unsigned short* __restrict__ qf, unsigned short* __restrict__ kf,
    unsigned short* __restrict__ vf, float* __restrict__ q2h, float* __restrict__ k2h)
{
  const int NQ = 393216, NV = 294912, NS = 12288;   // u32 counts (qf==kf)
  const int total = NQ + NQ + NV + 2 * NS;
  for (int idx = blockIdx.x * blockDim.x + threadIdx.x; idx < total; idx += gridDim.x * blockDim.x){
    int e = idx;
    if (e < 2 * NQ){
      bool isq = e < NQ; if (!isq) e -= NQ;
      int jjp = e & 3, l = (e >> 2) & 63, ks = (e >> 8) & 1;
      int t = e >> 9; int rt = t & 31; t >>= 5; int h = t % 12, b = t / 12;
      int row = rt * 16 + (l & 15);
      int k = ks * 32 + ((l >> 4) << 3) + jjp * 2;
      long bn = (long)b * 512 + row;
      int off = isq ? 0 : 384;
      float vs[2];
#pragma unroll
      for (int u = 0; u < 2; ++u){
        int kk = k + u; float v;
        if (kk < 32) v = proj[bn * NC1 + off + h * 32 + kk];
        else if (kk < 44) v = (isq ? qg : kg)[bn * 144 + h * 12 + (kk - 32)];
        else v = 0.f;
        vs[u] = v;
      }
      if (isq){ vs[0] *= SCALE; vs[1] *= SCALE; }
      ((unsigned*)(isq ? qf : kf))[e] = pack2(vs[0], vs[1]);
      continue;
    }
    e -= 2 * NQ;
    if (e < NV){
      int jjp = e & 3, l = (e >> 2) & 63;
      int t = e >> 8; int cf = t % 3; t /= 3; int jt = t & 15; t >>= 4;
      int h = t % 12, b = t / 12;
      int c = cf * 16 + (l & 15);
      int j = jt * 32 + ((l >> 4) << 3) + jjp * 2;
      float vs[2];
#pragma unroll
      for (int u = 0; u < 2; ++u){
        long bn = (long)b * 512 + j + u; float v;
        if (c < 32) v = proj[bn * NC1 + 768 + h * 32 + c];
        else if (c < 44) v = vg[bn * 144 + h * 12 + (c - 32)];
        else v = 0.f;
        vs[u] = v;
      }
      ((unsigned*)vf)[e] = pack2(vs[0], vs[1]);
      continue;
    }
    e -= NV;
    {
      bool isq = e < NS; if (!isq) e -= NS;
      int i = e & 511; int t = e >> 9; int h = t % 12, b = t / 12;
      long bn = (long)b * 512 + i;
      float s2 = (isq ? q2 : k2)[bn * 12 + h];
      float mv = mask[bn];
      float r = -0.5f * SCALE * s2 + (mv != 0.f ? 0.f : -2e9f);
      (isq ? q2h : k2h)[((long)b * 12 + h) * 512 + i] = r;
    }
  }
}

// ----------------------------- flash-style MFMA attention: 1 wave / 16 q-rows
__global__ __launch_bounds__(64) void attn2_kernel(
    const unsigned short* __restrict__ qf, const unsigned short* __restrict__ kf,
    const unsigned short* __restrict__ vf, const unsigned short* __restrict__ biasf,
    const float* __restrict__ q2h, const float* __restrict__ k2h,
    float* __restrict__ wsout, unsigned short* __restrict__ wpout)
{
  __shared__ unsigned short pls[2][16][40];   // P transpose scratch, row stride 80B
  int l = threadIdx.x;
  int qt = blockIdx.x, h = blockIdx.y, b = blockIdx.z;
  int bh = b * 12 + h;
  int g = l >> 4, q_ = l & 15;

  const short8* qp = (const short8*)(qf + (((long)(bh * 32 + qt) * 2) * 64 + l) * 8);
  short8 qA = qp[0], qB = qp[64];
  float cq = q2h[(long)bh * 512 + qt * 16 + q_];

  float m = -1e30f, ls = 0.f;
  f32x4 o0 = {0,0,0,0}, o1 = {0,0,0,0}, o2 = {0,0,0,0};
  const f32x4 z4 = {0,0,0,0};

#pragma unroll 2
  for (int jt = 0; jt < 16; ++jt){
    const short8* kp = (const short8*)(kf + (((long)(bh * 32 + jt * 2) * 2) * 64 + l) * 8);
    short8 k00 = kp[0], k01 = kp[64], k10 = kp[128], k11 = kp[192];
    f32x4 s0 = __builtin_amdgcn_mfma_f32_16x16x32_bf16(k00, qA, z4, 0, 0, 0);
    s0 = __builtin_amdgcn_mfma_f32_16x16x32_bf16(k01, qB, s0, 0, 0, 0);
    f32x4 s1 = __builtin_amdgcn_mfma_f32_16x16x32_bf16(k10, qA, z4, 0, 0, 0);
    s1 = __builtin_amdgcn_mfma_f32_16x16x32_bf16(k11, qB, s1, 0, 0, 0);

    const uint2* bp = (const uint2*)(biasf + ((((long)(bh * 16 + jt) * 32 + qt) * 2) * 64) * 4);
    uint2 bb0 = bp[l], bb1 = bp[64 + l];
    const float4* k2p = (const float4*)(k2h + (long)bh * 512 + jt * 32);
    float4 ck0 = k2p[g], ck1 = k2p[4 + g];

    s0[0] += bf_lo(bb0.x) + cq + ck0.x;
    s0[1] += bf_hi(bb0.x) + cq + ck0.y;
    s0[2] += bf_lo(bb0.y) + cq + ck0.z;
    s0[3] += bf_hi(bb0.y) + cq + ck0.w;
    s1[0] += bf_lo(bb1.x) + cq + ck1.x;
    s1[1] += bf_hi(bb1.x) + cq + ck1.y;
    s1[2] += bf_lo(bb1.y) + cq + ck1.z;
    s1[3] += bf_hi(bb1.y) + cq + ck1.w;

    float tm = fmaxf(fmaxf(fmaxf(s0[0], s0[1]), fmaxf(s0[2], s0[3])),
                     fmaxf(fmaxf(s1[0], s1[1]), fmaxf(s1[2], s1[3])));
    tm = fmaxf(tm, __shfl_xor(tm, 16));
    tm = fmaxf(tm, __shfl_xor(tm, 32));
    float mn = fmaxf(m, tm);
    float alpha = __expf(m - mn);
    f32x4 p0, p1;
    float ts = 0.f;
#pragma unroll
    for (int r = 0; r < 4; ++r){ p0[r] = __expf(s0[r] - mn); ts += p0[r]; }
#pragma unroll
    for (int r = 0; r < 4; ++r){ p1[r] = __expf(s1[r] - mn); ts += p1[r]; }
    ts += __shfl_xor(ts, 16);
    ts += __shfl_xor(ts, 32);
    ls = ls * alpha + ts; m = mn;

    f32x4 av;
#pragma unroll
    for (int r = 0; r < 4; ++r) av[r] = __shfl(alpha, g * 4 + r);
#pragma unroll
    for (int r = 0; r < 4; ++r){ o0[r] *= av[r]; o1[r] *= av[r]; o2[r] *= av[r]; }

    // P -> LDS (bf16, [q][jloc]) -> A fragment
    uint2 w0; w0.x = pack2(p0[0], p0[1]); w0.y = pack2(p0[2], p0[3]);
    uint2 w1; w1.x = pack2(p1[0], p1[1]); w1.y = pack2(p1[2], p1[3]);
    int bufi = jt & 1;
    *(uint2*)&pls[bufi][q_][g * 4]      = w0;
    *(uint2*)&pls[bufi][q_][16 + g * 4] = w1;
    short8 pa = *(const short8*)&pls[bufi][q_][g * 8];

    const short8* vp = (const short8*)(vf + (((long)(bh * 16 + jt) * 3) * 64 + l) * 8);
    short8 v0 = vp[0], v1 = vp[64], v2 = vp[128];
    o0 = __builtin_amdgcn_mfma_f32_16x16x32_bf16(pa, v0, o0, 0, 0, 0);
    o1 = __builtin_amdgcn_mfma_f32_16x16x32_bf16(pa, v1, o1, 0, 0, 0);
    o2 = __builtin_amdgcn_mfma_f32_16x16x32_bf16(pa, v2, o2, 0, 0, 0);
  }

  float inv = 1.f / ls;
  f32x4 iv;
#pragma unroll
  for (int r = 0; r < 4; ++r) iv[r] = __shfl(inv, g * 4 + r);
#pragma unroll
  for (int r = 0; r < 4; ++r){
    long bn = (long)b * 512 + qt * 16 + g * 4 + r;
    wsout[bn * 384 + h * 32 + q_]      = o0[r] * iv[r];
    wsout[bn * 384 + h * 32 + 16 + q_] = o1[r] * iv[r];
    if (q_ < 12) wpout[bn * 160 + h * 12 + q_] = f2bf(o2[r] * iv[r]);
  }
}

// ---------------------------------------------------------------- layer norm
__global__ __launch_bounds__(256) void ln_kernel(
    const float* __restrict__ x, const float* __restrict__ g,
    const float* __restrict__ bta, float* __restrict__ out)
{
  int wv = threadIdx.x >> 6, ln = threadIdx.x & 63;
  long row = (long)blockIdx.x * 4 + wv;
  const float* xr = x + row * 384;
  float v[6]; float s = 0.f, s2 = 0.f;
#pragma unroll
  for (int i = 0; i < 6; ++i){
    v[i] = xr[ln + i * 64]; s += v[i]; s2 += v[i] * v[i];
  }
  for (int off = 32; off; off >>= 1){ s += __shfl_xor(s, off); s2 += __shfl_xor(s2, off); }
  float mu = s * (1.f / 384.f);
  float var = s2 * (1.f / 384.f) - mu * mu;
  float inv = rsqrtf(var + 1e-5f);
  float* orow = out + row * 384;
#pragma unroll
  for (int i = 0; i < 6; ++i){
    int c = ln + i * 64;
    orow[c] = (v[i] - mu) * inv * g[c] + bta[c];
  }
}

// -------------------------------------------------------------------- launcher
extern "C" void kernel_launch(void* const* d_in, const int* in_sizes, int n_in,
                              void* d_out, int out_size, void* d_ws, size_t ws_size,
                              hipStream_t stream)
{
  const float* single = (const float*)d_in[0];
  const float* pair   = (const float*)d_in[1];
  const float* rot    = (const float*)d_in[2];
  const float* trans  = (const float*)d_in[3];
  const float* mask   = (const float*)d_in[4];
  const float* Wq  = (const float*)d_in[5];  const float* bq  = (const float*)d_in[6];
  const float* Wk  = (const float*)d_in[7];  const float* bk  = (const float*)d_in[8];
  const float* Wv  = (const float*)d_in[9];  const float* bv  = (const float*)d_in[10];
  const float* Wpb = (const float*)d_in[11]; const float* bpb = (const float*)d_in[12];
  const float* Wqp = (const float*)d_in[13]; const float* bqp = (const float*)d_in[14];
  const float* Wkp = (const float*)d_in[15]; const float* bkp = (const float*)d_in[16];
  const float* Wvp = (const float*)d_in[17]; const float* bvp = (const float*)d_in[18];
  const float* Wo  = (const float*)d_in[19]; const float* bo  = (const float*)d_in[20];
  const float* Wpo = (const float*)d_in[21]; const float* bpo = (const float*)d_in[22];
  const float* ln_g = (const float*)d_in[23]; const float* ln_b = (const float*)d_in[24];

  char* wsb = (char*)d_ws;
  size_t off = 0;
  auto alloc = [&](size_t bytes) -> void* {
    void* p = wsb + off; off += (bytes + 255) & ~(size_t)255; return p;
  };
  unsigned short* sbf  = (unsigned short*)alloc((size_t)BN * Cc * 2);
  unsigned short* wcat = (unsigned short*)alloc((size_t)12 * CT1 * 512 * 2);
  unsigned short* wpof = (unsigned short*)alloc((size_t)5 * 24 * 512 * 2);
  unsigned short* wof  = (unsigned short*)alloc((size_t)12 * 24 * 512 * 2);
  float* bcat  = (float*)alloc(NC1 * 4);
  float* proj  = (float*)alloc((size_t)BN * NC1 * 4);
  float* qgb   = (float*)alloc((size_t)BN * 144 * 4);
  float* kgb   = (float*)alloc((size_t)BN * 144 * 4);
  float* vgb   = (float*)alloc((size_t)BN * 144 * 4);
  float* q2b   = (float*)alloc((size_t)BN * 12 * 4);
  float* k2b   = (float*)alloc((size_t)BN * 12 * 4);
  unsigned short* biasf = (unsigned short*)alloc((size_t)Bb * Hh * Nn * Nn * 2);
  unsigned short* qfragb = (unsigned short*)alloc((size_t)786432 * 2);
  unsigned short* kfragb = (unsigned short*)alloc((size_t)786432 * 2);
  unsigned short* vfragb = (unsigned short*)alloc((size_t)589824 * 2);
  float* q2hb  = (float*)alloc((size_t)12288 * 4);
  float* k2hb  = (float*)alloc((size_t)12288 * 4);
  float* wso   = (float*)alloc((size_t)BN * 384 * 4);
  unsigned short* wpbuf = (unsigned short*)alloc((size_t)BN * 160 * 2);
  unsigned short* t1    = (unsigned short*)alloc((size_t)BN * 384 * 2);
  float* xbuf  = (float*)alloc((size_t)BN * 384 * 4);
  if (off > ws_size) return;

  PrepArgs pa;
  pa.single = single; pa.Wq = Wq; pa.Wk = Wk; pa.Wv = Wv;
  pa.Wqp = Wqp; pa.Wkp = Wkp; pa.Wvp = Wvp; pa.Wpo = Wpo; pa.Wo = Wo;
  pa.bq = bq; pa.bk = bk; pa.bv = bv; pa.bqp = bqp; pa.bkp = bkp; pa.bvp = bvp;
  pa.sbf = sbf; pa.wcat = wcat; pa.wpof = wpof; pa.wof = wof; pa.wppad = wpbuf;
  pa.bcat = bcat;

  prep_kernel<<<512, 256, 0, stream>>>(pa);
  gemm_mfma<<<dim3(16, 33), 256, 0, stream>>>(sbf, Cc, 12, wcat, CT1, bcat,
                                              nullptr, proj, nullptr, NC1);
  transform_kernel<<<144, 256, 0, stream>>>(proj, rot, trans, qgb, kgb, vgb, q2b, k2b);
  pack_kernel<<<1024, 256, 0, stream>>>(proj, qgb, kgb, vgb, q2b, k2b, mask,
                                        qfragb, kfragb, vfragb, q2hb, k2hb);
  bias_kernel<<<8192, 256, 0, stream>>>(pair, Wpb, bpb, biasf);
  attn2_kernel<<<dim3(32, 12, 2), 64, 0, stream>>>(qfragb, kfragb, vfragb, biasf,
                                                   q2hb, k2hb, wso, wpbuf);
  gemm_mfma<<<dim3(16, 8), 256, 0, stream>>>(wpbuf, 160, 5, wpof, 24, bpo,
                                             wso, nullptr, t1, 384);
  gemm_mfma<<<dim3(16, 8), 256, 0, stream>>>(t1, 384, 12, wof, 24, bo,
                                             single, xbuf, nullptr, 384);
  ln_kernel<<<256, 256, 0, stream>>>(xbuf, ln_g, ln_b, (float*)d_out);
}

// Round 3
// 128.715 us; speedup vs baseline: 2.1363x; 1.0340x over previous
//
#include <hip/hip_runtime.h>
#include <hip/hip_bf16.h>

// Problem constants
#define Bb   2
#define Nn   512
#define Cc   384
#define Hh   12
#define Pp   4
#define DPp  128
#define CHh  32
#define BN   1024          // B*N
#define NC1  1584          // 3*384 + 3*144 concatenated proj cols
#define CT1  99            // 1584/16 col-tiles
#define SCALE 0.17677669529663687f   // 32^-0.5

typedef __attribute__((ext_vector_type(8))) short short8;
typedef __attribute__((ext_vector_type(4))) float f32x4;

__device__ __forceinline__ unsigned short f2bf(float f){
  union { float f; unsigned u; } v; v.f = f;
  unsigned u = v.u;
  unsigned r = u + 0x7fffu + ((u >> 16) & 1u);
  return (unsigned short)(r >> 16);
}
__device__ __forceinline__ float bf_lo(unsigned u){ union{unsigned u; float f;} v; v.u = u << 16; return v.f; }
__device__ __forceinline__ float bf_hi(unsigned u){ union{unsigned u; float f;} v; v.u = u & 0xffff0000u; return v.f; }
__device__ __forceinline__ unsigned pack2(float a, float b){
  return (unsigned)f2bf(a) | ((unsigned)f2bf(b) << 16);
}

// ----------------------------------------------- prep: sbf + wcat + bcat only
struct PrepArgs {
  const float *single, *Wq, *Wk, *Wv, *Wqp, *Wkp, *Wvp;
  const float *bq, *bk, *bv, *bqp, *bkp, *bvp;
  unsigned short *sbf, *wcat;
  float *bcat;
};

__global__ void prep_kernel(PrepArgs pa){
  const int n0 = BN * Cc;            // single -> bf16
  const int n1 = 12 * CT1 * 512;     // wcat frag elems
  const int n4 = NC1;                // concat bias
  const int total = n0 + n1 + n4;
  for (int i = blockIdx.x * blockDim.x + threadIdx.x; i < total; i += gridDim.x * blockDim.x){
    int e = i;
    if (e < n0){ pa.sbf[e] = f2bf(pa.single[e]); continue; }
    e -= n0;
    if (e < n1){
      int j8 = e & 7, l = (e >> 3) & 63, ctt = e >> 9;
      int ct = ctt % CT1, t = ctt / CT1;
      int k = t * 32 + ((l >> 4) << 3) + j8;
      int col = (ct << 4) + (l & 15);
      float v;
      if (col < 1152){
        const float* W = (col < 384) ? pa.Wq : (col < 768 ? pa.Wk : pa.Wv);
        v = W[k * 384 + (col % 384)];
      } else {
        int c2 = col - 1152;
        const float* W = (c2 < 144) ? pa.Wqp : (c2 < 288 ? pa.Wkp : pa.Wvp);
        v = W[k * 144 + (c2 % 144)];
      }
      pa.wcat[e] = f2bf(v); continue;
    }
    e -= n1;
    {
      int col = e; float v;
      if (col < 1152){
        const float* bb = (col < 384) ? pa.bq : (col < 768 ? pa.bk : pa.bv);
        v = bb[col % 384];
      } else {
        int c2 = col - 1152;
        const float* bb = (c2 < 144) ? pa.bqp : (c2 < 288 ? pa.bkp : pa.bvp);
        v = bb[c2 % 144];
      }
      pa.bcat[col] = v;
    }
  }
}

// ------------------------------------------------------------ generic MFMA GEMM
__global__ __launch_bounds__(256) void gemm_mfma(
    const unsigned short* __restrict__ A, int lda, int ksteps,
    const unsigned short* __restrict__ wfrag, int ct_total,
    const float* __restrict__ bias, float* __restrict__ outf, int ncols)
{
  int l = threadIdx.x & 63, w = threadIdx.x >> 6;
  int m0 = blockIdx.x * 64 + w * 16;
  const unsigned short* Ap = A + (long)(m0 + (l & 15)) * lda + ((l >> 4) << 3);
  int ct0 = blockIdx.y * 3;
  f32x4 acc0 = {0,0,0,0}, acc1 = {0,0,0,0}, acc2 = {0,0,0,0};
  for (int t = 0; t < ksteps; ++t){
    short8 a = *(const short8*)(Ap + t * 32);
    const unsigned short* wp_ = wfrag + ((long)(t * ct_total + ct0) * 64 + l) * 8;
    short8 b0 = *(const short8*)(wp_);
    short8 b1 = *(const short8*)(wp_ + 512);
    short8 b2 = *(const short8*)(wp_ + 1024);
    acc0 = __builtin_amdgcn_mfma_f32_16x16x32_bf16(a, b0, acc0, 0, 0, 0);
    acc1 = __builtin_amdgcn_mfma_f32_16x16x32_bf16(a, b1, acc1, 0, 0, 0);
    acc2 = __builtin_amdgcn_mfma_f32_16x16x32_bf16(a, b2, acc2, 0, 0, 0);
  }
  int rbase = m0 + ((l >> 4) << 2);
  int cb = blockIdx.y * 48 + (l & 15);
#pragma unroll
  for (int c = 0; c < 3; ++c){
    f32x4 ac = (c == 0) ? acc0 : (c == 1 ? acc1 : acc2);
    int col = cb + c * 16;
    float bb = bias[col];
#pragma unroll
    for (int r = 0; r < 4; ++r){
      long idx = (long)(rbase + r) * ncols + col;
      outf[idx] = ac[r] + bb;
    }
  }
}

// --------------------- megapack: bias MFMA + pack(+transform) + tail-frag prep
// blocks [0,8192): pair bias -> bf16 S-fragment layout
// blocks [8192, 8192+5200): elementwise jobs
__global__ __launch_bounds__(256) void megapack_kernel(
    const float* __restrict__ pair, const float* __restrict__ Wpb,
    const float* __restrict__ bpb,
    const float* __restrict__ proj, const float* __restrict__ rot,
    const float* __restrict__ trans, const float* __restrict__ mask,
    const float* __restrict__ Wpo, const float* __restrict__ Wo,
    unsigned short* __restrict__ biasf,
    unsigned short* __restrict__ qf, unsigned short* __restrict__ kf,
    unsigned short* __restrict__ vf,
    float* __restrict__ q2h, float* __restrict__ k2h,
    unsigned short* __restrict__ wpof, unsigned short* __restrict__ wof,
    unsigned short* __restrict__ wppad)
{
  if (blockIdx.x < 8192){
    int l = threadIdx.x & 63, w = threadIdx.x >> 6;
    long m0 = (long)blockIdx.x * 64 + w * 16;
    long m = m0 + (l & 15);
    int kb = (l >> 4) << 3;
    int col = l & 15;
    short8 bf[4];
#pragma unroll
    for (int t = 0; t < 4; ++t){
#pragma unroll
      for (int j = 0; j < 8; ++j){
        int k = t * 32 + kb + j;
        float v = (col < 12) ? Wpb[k * 12 + col] : 0.f;
        bf[t][j] = (short)f2bf(v);
      }
    }
    const float* pr = pair + m * 128 + kb;
    f32x4 acc = {0,0,0,0};
#pragma unroll
    for (int t = 0; t < 4; ++t){
      float4 x0 = *(const float4*)(pr + t * 32);
      float4 x1 = *(const float4*)(pr + t * 32 + 4);
      short8 a;
      a[0] = (short)f2bf(x0.x); a[1] = (short)f2bf(x0.y);
      a[2] = (short)f2bf(x0.z); a[3] = (short)f2bf(x0.w);
      a[4] = (short)f2bf(x1.x); a[5] = (short)f2bf(x1.y);
      a[6] = (short)f2bf(x1.z); a[7] = (short)f2bf(x1.w);
      acc = __builtin_amdgcn_mfma_f32_16x16x32_bf16(a, bf[t], acc, 0, 0, 0);
    }
    int h = col;
    if (h < 12){
      long mr = m0 + ((l >> 4) << 2);
      int b  = (int)(mr >> 18);
      int i  = (int)((mr >> 9) & 511);
      int j  = (int)(mr & 511);
      int jt = j >> 5, f = (j >> 4) & 1, g2 = (j >> 2) & 3;
      int qt = i >> 4, q = i & 15;
      float bb = bpb[h];
      long e16 = (((((long)((b * 12 + h) * 16 + jt) * 32 + qt) * 2 + f) * 64) + (g2 * 16 + q)) * 4;
      uint2 wv; wv.x = pack2(acc[0] + bb, acc[1] + bb); wv.y = pack2(acc[2] + bb, acc[3] + bb);
      *(uint2*)(biasf + e16) = wv;
    }
    return;
  }

  int e = (blockIdx.x - 8192) * 256 + threadIdx.x;
  const int EQ = 786432, EV = 294912, ES = 24576, EP1 = 61440, EP2 = 147456;
  if (e < EQ){
    bool isq = e < 393216; if (!isq) e -= 393216;
    int jjp = e & 3, l = (e >> 2) & 63, ks = (e >> 8) & 1;
    int t = e >> 9; int rt = t & 31; t >>= 5; int h = t % 12, b = t / 12;
    int row = rt * 16 + (l & 15);
    int k = ks * 32 + ((l >> 4) << 3) + jjp * 2;
    long bn = (long)b * 512 + row;
    int off = isq ? 0 : 384;
    int a = isq ? 0 : 1;
    const float* R = rot + bn * 9;
    const float* T = trans + bn * 3;
    float vs[2];
#pragma unroll
    for (int u = 0; u < 2; ++u){
      int kk = k + u; float v;
      if (kk < 32) v = proj[bn * NC1 + off + h * 32 + kk];
      else if (kk < 44){
        int pe = kk - 32, p = pe / 3, ee = pe % 3;
        const float* ps = proj + bn * NC1 + 1152 + a * 144 + h * 12 + p * 3;
        v = ps[0] * R[ee] + ps[1] * R[3 + ee] + ps[2] * R[6 + ee] + T[ee];
      } else v = 0.f;
      vs[u] = v;
    }
    if (isq){ vs[0] *= SCALE; vs[1] *= SCALE; }
    ((unsigned*)(isq ? qf : kf))[e] = pack2(vs[0], vs[1]);
    return;
  }
  e -= EQ;
  if (e < EV){
    int jjp = e & 3, l = (e >> 2) & 63;
    int t = e >> 8; int cf = t % 3; t /= 3; int jt = t & 15; t >>= 4;
    int h = t % 12, b = t / 12;
    int c = cf * 16 + (l & 15);
    int j = jt * 32 + ((l >> 4) << 3) + jjp * 2;
    float vs[2];
#pragma unroll
    for (int u = 0; u < 2; ++u){
      long bn = (long)b * 512 + j + u; float v;
      if (c < 32) v = proj[bn * NC1 + 768 + h * 32 + c];
      else if (c < 44){
        int pe = c - 32, p = pe / 3, ee = pe % 3;
        const float* ps = proj + bn * NC1 + 1152 + 288 + h * 12 + p * 3;
        const float* R = rot + bn * 9;
        v = ps[0] * R[ee] + ps[1] * R[3 + ee] + ps[2] * R[6 + ee] + trans[bn * 3 + ee];
      } else v = 0.f;
      vs[u] = v;
    }
    ((unsigned*)vf)[e] = pack2(vs[0], vs[1]);
    return;
  }
  e -= EV;
  if (e < ES){
    bool isq = e < 12288; if (!isq) e -= 12288;
    int i = e & 511; int t = e >> 9; int h = t % 12, b = t / 12;
    long bn = (long)b * 512 + i;
    const float* R = rot + bn * 9;
    const float* T = trans + bn * 3;
    const float* ps0 = proj + bn * NC1 + 1152 + (isq ? 0 : 144) + h * 12;
    float s2 = 0.f;
#pragma unroll
    for (int p = 0; p < 4; ++p){
      float d0 = ps0[p * 3], d1 = ps0[p * 3 + 1], d2 = ps0[p * 3 + 2];
#pragma unroll
      for (int ee = 0; ee < 3; ++ee){
        float g = d0 * R[ee] + d1 * R[3 + ee] + d2 * R[6 + ee] + T[ee];
        s2 += g * g;
      }
    }
    float mv = mask[bn];
    float r = -0.5f * SCALE * s2 + (mv != 0.f ? 0.f : -2e9f);
    (isq ? q2h : k2h)[((long)b * 12 + h) * 512 + i] = r;
    return;
  }
  e -= ES;
  if (e < EP1){
    int j8 = e & 7, l = (e >> 3) & 63, ctt = e >> 9;
    int ct = ctt % 24, t = ctt / 24;
    int k = t * 32 + ((l >> 4) << 3) + j8;
    int col = (ct << 4) + (l & 15);
    wpof[e] = (k < 144) ? f2bf(Wpo[k * 384 + col]) : (unsigned short)0;
    return;
  }
  e -= EP1;
  if (e < EP2){
    int j8 = e & 7, l = (e >> 3) & 63, ctt = e >> 9;
    int ct = ctt % 24, t = ctt / 24;
    int k = t * 32 + ((l >> 4) << 3) + j8;
    int col = (ct << 4) + (l & 15);
    wof[e] = f2bf(Wo[k * 384 + col]);
    return;
  }
  e -= EP2;
  { int row = e >> 4, c = e & 15; wppad[row * 160 + 144 + c] = 0; }
}

// ----------------------------- flash-style MFMA attention: 1 wave / 16 q-rows
__global__ __launch_bounds__(64) void attn2_kernel(
    const unsigned short* __restrict__ qf, const unsigned short* __restrict__ kf,
    const unsigned short* __restrict__ vf, const unsigned short* __restrict__ biasf,
    const float* __restrict__ q2h, const float* __restrict__ k2h,
    float* __restrict__ wsout, unsigned short* __restrict__ wpout)
{
  __shared__ unsigned short pls[2][16][40];
  int l = threadIdx.x;
  int qt = blockIdx.x, h = blockIdx.y, b = blockIdx.z;
  int bh = b * 12 + h;
  int g = l >> 4, q_ = l & 15;

  const short8* qp = (const short8*)(qf + (((long)(bh * 32 + qt) * 2) * 64 + l) * 8);
  short8 qA = qp[0], qB = qp[64];
  float cq = q2h[(long)bh * 512 + qt * 16 + q_];

  float m = -1e30f, ls = 0.f;
  f32x4 o0 = {0,0,0,0}, o1 = {0,0,0,0}, o2 = {0,0,0,0};
  const f32x4 z4 = {0,0,0,0};

#pragma unroll 2
  for (int jt = 0; jt < 16; ++jt){
    const short8* kp = (const short8*)(kf + (((long)(bh * 32 + jt * 2) * 2) * 64 + l) * 8);
    short8 k00 = kp[0], k01 = kp[64], k10 = kp[128], k11 = kp[192];
    f32x4 s0 = __builtin_amdgcn_mfma_f32_16x16x32_bf16(k00, qA, z4, 0, 0, 0);
    s0 = __builtin_amdgcn_mfma_f32_16x16x32_bf16(k01, qB, s0, 0, 0, 0);
    f32x4 s1 = __builtin_amdgcn_mfma_f32_16x16x32_bf16(k10, qA, z4, 0, 0, 0);
    s1 = __builtin_amdgcn_mfma_f32_16x16x32_bf16(k11, qB, s1, 0, 0, 0);

    const uint2* bp = (const uint2*)(biasf + ((((long)(bh * 16 + jt) * 32 + qt) * 2) * 64) * 4);
    uint2 bb0 = bp[l], bb1 = bp[64 + l];
    const float4* k2p = (const float4*)(k2h + (long)bh * 512 + jt * 32);
    float4 ck0 = k2p[g], ck1 = k2p[4 + g];

    s0[0] += bf_lo(bb0.x) + cq + ck0.x;
    s0[1] += bf_hi(bb0.x) + cq + ck0.y;
    s0[2] += bf_lo(bb0.y) + cq + ck0.z;
    s0[3] += bf_hi(bb0.y) + cq + ck0.w;
    s1[0] += bf_lo(bb1.x) + cq + ck1.x;
    s1[1] += bf_hi(bb1.x) + cq + ck1.y;
    s1[2] += bf_lo(bb1.y) + cq + ck1.z;
    s1[3] += bf_hi(bb1.y) + cq + ck1.w;

    float tm = fmaxf(fmaxf(fmaxf(s0[0], s0[1]), fmaxf(s0[2], s0[3])),
                     fmaxf(fmaxf(s1[0], s1[1]), fmaxf(s1[2], s1[3])));
    tm = fmaxf(tm, __shfl_xor(tm, 16));
    tm = fmaxf(tm, __shfl_xor(tm, 32));
    float mn = fmaxf(m, tm);
    float alpha = __expf(m - mn);
    f32x4 p0, p1;
    float ts = 0.f;
#pragma unroll
    for (int r = 0; r < 4; ++r){ p0[r] = __expf(s0[r] - mn); ts += p0[r]; }
#pragma unroll
    for (int r = 0; r < 4; ++r){ p1[r] = __expf(s1[r] - mn); ts += p1[r]; }
    ts += __shfl_xor(ts, 16);
    ts += __shfl_xor(ts, 32);
    ls = ls * alpha + ts; m = mn;

    f32x4 av;
#pragma unroll
    for (int r = 0; r < 4; ++r) av[r] = __shfl(alpha, g * 4 + r);
#pragma unroll
    for (int r = 0; r < 4; ++r){ o0[r] *= av[r]; o1[r] *= av[r]; o2[r] *= av[r]; }

    uint2 w0; w0.x = pack2(p0[0], p0[1]); w0.y = pack2(p0[2], p0[3]);
    uint2 w1; w1.x = pack2(p1[0], p1[1]); w1.y = pack2(p1[2], p1[3]);
    int bufi = jt & 1;
    *(uint2*)&pls[bufi][q_][g * 4]      = w0;
    *(uint2*)&pls[bufi][q_][16 + g * 4] = w1;
    short8 pa = *(const short8*)&pls[bufi][q_][g * 8];

    const short8* vp = (const short8*)(vf + (((long)(bh * 16 + jt) * 3) * 64 + l) * 8);
    short8 v0 = vp[0], v1 = vp[64], v2 = vp[128];
    o0 = __builtin_amdgcn_mfma_f32_16x16x32_bf16(pa, v0, o0, 0, 0, 0);
    o1 = __builtin_amdgcn_mfma_f32_16x16x32_bf16(pa, v1, o1, 0, 0, 0);
    o2 = __builtin_amdgcn_mfma_f32_16x16x32_bf16(pa, v2, o2, 0, 0, 0);
  }

  float inv = 1.f / ls;
  f32x4 iv;
#pragma unroll
  for (int r = 0; r < 4; ++r) iv[r] = __shfl(inv, g * 4 + r);
#pragma unroll
  for (int r = 0; r < 4; ++r){
    long bn = (long)b * 512 + qt * 16 + g * 4 + r;
    wsout[bn * 384 + h * 32 + q_]      = o0[r] * iv[r];
    wsout[bn * 384 + h * 32 + 16 + q_] = o1[r] * iv[r];
    if (q_ < 12) wpout[bn * 160 + h * 12 + q_] = f2bf(o2[r] * iv[r]);
  }
}

// ------------------------- tail: wp@Wpo + wso -> t1; t1@Wo + single -> LN -> out
__global__ __launch_bounds__(256) void tail_kernel(
    const unsigned short* __restrict__ wpbuf, const unsigned short* __restrict__ wpof,
    const float* __restrict__ bpo, const float* __restrict__ wso,
    const unsigned short* __restrict__ wof, const float* __restrict__ bo,
    const float* __restrict__ single, const float* __restrict__ ln_g,
    const float* __restrict__ ln_b, float* __restrict__ out)
{
  __shared__ unsigned short t1s[64][392];
  int l = threadIdx.x & 63, w = threadIdx.x >> 6;
  int m0 = blockIdx.x * 64;
  int rb = w * 16 + ((l >> 4) << 2);          // local C row base
  int arow = m0 + w * 16 + (l & 15);          // A row this lane serves

  // stage 1: t1 = wp @ Wpo + bpo + wso
  short8 awp[5];
  {
    const unsigned short* Ap = wpbuf + (long)arow * 160 + ((l >> 4) << 3);
#pragma unroll
    for (int t = 0; t < 5; ++t) awp[t] = *(const short8*)(Ap + t * 32);
  }
#pragma unroll 4
  for (int ct = 0; ct < 24; ++ct){
    f32x4 acc = {0,0,0,0};
#pragma unroll
    for (int t = 0; t < 5; ++t){
      short8 bfr = *(const short8*)(wpof + ((long)(t * 24 + ct) * 64 + l) * 8);
      acc = __builtin_amdgcn_mfma_f32_16x16x32_bf16(awp[t], bfr, acc, 0, 0, 0);
    }
    int col = ct * 16 + (l & 15);
    float bb = bpo[col];
#pragma unroll
    for (int r = 0; r < 4; ++r){
      float v = acc[r] + bb + wso[(long)(m0 + rb + r) * 384 + col];
      t1s[rb + r][col] = f2bf(v);
    }
  }
  __syncthreads();

  // stage 2: x = t1 @ Wo + bo + single; collect row sums for LN
  short8 a2[12];
  {
    int lr = w * 16 + (l & 15);
#pragma unroll
    for (int t = 0; t < 12; ++t)
      a2[t] = *(const short8*)&t1s[lr][t * 32 + ((l >> 4) << 3)];
  }
  f32x4 xa[24];
  float s1[4] = {0,0,0,0}, s2[4] = {0,0,0,0};
#pragma unroll
  for (int ct = 0; ct < 24; ++ct){
    f32x4 acc = {0,0,0,0};
#pragma unroll
    for (int t = 0; t < 12; ++t){
      short8 bfr = *(const short8*)(wof + ((long)(t * 24 + ct) * 64 + l) * 8);
      acc = __builtin_amdgcn_mfma_f32_16x16x32_bf16(a2[t], bfr, acc, 0, 0, 0);
    }
    int col = ct * 16 + (l & 15);
    float bb = bo[col];
#pragma unroll
    for (int r = 0; r < 4; ++r){
      float v = acc[r] + bb + single[(long)(m0 + rb + r) * 384 + col];
      acc[r] = v; s1[r] += v; s2[r] += v * v;
    }
    xa[ct] = acc;
  }
#pragma unroll
  for (int off = 1; off < 16; off <<= 1){
#pragma unroll
    for (int r = 0; r < 4; ++r){
      s1[r] += __shfl_xor(s1[r], off);
      s2[r] += __shfl_xor(s2[r], off);
    }
  }
  float mu[4], inv[4];
#pragma unroll
  for (int r = 0; r < 4; ++r){
    mu[r] = s1[r] * (1.f / 384.f);
    float var = s2[r] * (1.f / 384.f) - mu[r] * mu[r];
    inv[r] = rsqrtf(var + 1e-5f);
  }
#pragma unroll
  for (int ct = 0; ct < 24; ++ct){
    int col = ct * 16 + (l & 15);
    float g = ln_g[col], bt = ln_b[col];
#pragma unroll
    for (int r = 0; r < 4; ++r)
      out[(long)(m0 + rb + r) * 384 + col] = (xa[ct][r] - mu[r]) * inv[r] * g + bt;
  }
}

// -------------------------------------------------------------------- launcher
extern "C" void kernel_launch(void* const* d_in, const int* in_sizes, int n_in,
                              void* d_out, int out_size, void* d_ws, size_t ws_size,
                              hipStream_t stream)
{
  const float* single = (const float*)d_in[0];
  const float* pair   = (const float*)d_in[1];
  const float* rot    = (const float*)d_in[2];
  const float* trans  = (const float*)d_in[3];
  const float* mask   = (const float*)d_in[4];
  const float* Wq  = (const float*)d_in[5];  const float* bq  = (const float*)d_in[6];
  const float* Wk  = (const float*)d_in[7];  const float* bk  = (const float*)d_in[8];
  const float* Wv  = (const float*)d_in[9];  const float* bv  = (const float*)d_in[10];
  const float* Wpb = (const float*)d_in[11]; const float* bpb = (const float*)d_in[12];
  const float* Wqp = (const float*)d_in[13]; const float* bqp = (const float*)d_in[14];
  const float* Wkp = (const float*)d_in[15]; const float* bkp = (const float*)d_in[16];
  const float* Wvp = (const float*)d_in[17]; const float* bvp = (const float*)d_in[18];
  const float* Wo  = (const float*)d_in[19]; const float* bo  = (const float*)d_in[20];
  const float* Wpo = (const float*)d_in[21]; const float* bpo = (const float*)d_in[22];
  const float* ln_g = (const float*)d_in[23]; const float* ln_b = (const float*)d_in[24];

  char* wsb = (char*)d_ws;
  size_t off = 0;
  auto alloc = [&](size_t bytes) -> void* {
    void* p = wsb + off; off += (bytes + 255) & ~(size_t)255; return p;
  };
  unsigned short* sbf  = (unsigned short*)alloc((size_t)BN * Cc * 2);
  unsigned short* wcat = (unsigned short*)alloc((size_t)12 * CT1 * 512 * 2);
  unsigned short* wpof = (unsigned short*)alloc((size_t)5 * 24 * 512 * 2);
  unsigned short* wof  = (unsigned short*)alloc((size_t)12 * 24 * 512 * 2);
  float* bcat  = (float*)alloc(NC1 * 4);
  float* proj  = (float*)alloc((size_t)BN * NC1 * 4);
  unsigned short* biasf = (unsigned short*)alloc((size_t)Bb * Hh * Nn * Nn * 2);
  unsigned short* qfragb = (unsigned short*)alloc((size_t)786432 * 2);
  unsigned short* kfragb = (unsigned short*)alloc((size_t)786432 * 2);
  unsigned short* vfragb = (unsigned short*)alloc((size_t)589824 * 2);
  float* q2hb  = (float*)alloc((size_t)12288 * 4);
  float* k2hb  = (float*)alloc((size_t)12288 * 4);
  float* wso   = (float*)alloc((size_t)BN * 384 * 4);
  unsigned short* wpbuf = (unsigned short*)alloc((size_t)BN * 160 * 2);
  if (off > ws_size) return;

  PrepArgs pa;
  pa.single = single; pa.Wq = Wq; pa.Wk = Wk; pa.Wv = Wv;
  pa.Wqp = Wqp; pa.Wkp = Wkp; pa.Wvp = Wvp;
  pa.bq = bq; pa.bk = bk; pa.bv = bv; pa.bqp = bqp; pa.bkp = bkp; pa.bvp = bvp;
  pa.sbf = sbf; pa.wcat = wcat; pa.bcat = bcat;

  prep_kernel<<<512, 256, 0, stream>>>(pa);
  gemm_mfma<<<dim3(16, 33), 256, 0, stream>>>(sbf, Cc, 12, wcat, CT1, bcat, proj, NC1);
  megapack_kernel<<<8192 + 5200, 256, 0, stream>>>(
      pair, Wpb, bpb, proj, rot, trans, mask, Wpo, Wo,
      biasf, qfragb, kfragb, vfragb, q2hb, k2hb, wpof, wof, wpbuf);
  attn2_kernel<<<dim3(32, 12, 2), 64, 0, stream>>>(qfragb, kfragb, vfragb, biasf,
                                                   q2hb, k2hb, wso, wpbuf);
  tail_kernel<<<16, 256, 0, stream>>>(wpbuf, wpof, bpo, wso, wof, bo,
                                      single, ln_g, ln_b, (float*)d_out);
}

// Round 4
// 126.915 us; speedup vs baseline: 2.1666x; 1.0142x over previous
//
#include <hip/hip_runtime.h>
#include <hip/hip_bf16.h>

// Problem constants
#define Bb   2
#define Nn   512
#define Cc   384
#define Hh   12
#define Pp   4
#define DPp  128
#define CHh  32
#define BN   1024          // B*N
#define NC1  1584          // 3*384 + 3*144 concatenated proj cols
#define CT1  99            // 1584/16 col-tiles
#define SCALE 0.17677669529663687f   // 32^-0.5

typedef __attribute__((ext_vector_type(8))) short short8;
typedef __attribute__((ext_vector_type(4))) float f32x4;

__device__ __forceinline__ unsigned short f2bf(float f){
  union { float f; unsigned u; } v; v.f = f;
  unsigned u = v.u;
  unsigned r = u + 0x7fffu + ((u >> 16) & 1u);
  return (unsigned short)(r >> 16);
}
__device__ __forceinline__ float bf_lo(unsigned u){ union{unsigned u; float f;} v; v.u = u << 16; return v.f; }
__device__ __forceinline__ float bf_hi(unsigned u){ union{unsigned u; float f;} v; v.u = u & 0xffff0000u; return v.f; }
__device__ __forceinline__ unsigned pack2(float a, float b){
  return (unsigned)f2bf(a) | ((unsigned)f2bf(b) << 16);
}

// ----------------------------------------------- prep: sbf + wcat + bcat only
struct PrepArgs {
  const float *single, *Wq, *Wk, *Wv, *Wqp, *Wkp, *Wvp;
  const float *bq, *bk, *bv, *bqp, *bkp, *bvp;
  unsigned short *sbf, *wcat;
  float *bcat;
};

__global__ void prep_kernel(PrepArgs pa){
  const int n0 = BN * Cc;
  const int n1 = 12 * CT1 * 512;
  const int n4 = NC1;
  const int total = n0 + n1 + n4;
  for (int i = blockIdx.x * blockDim.x + threadIdx.x; i < total; i += gridDim.x * blockDim.x){
    int e = i;
    if (e < n0){ pa.sbf[e] = f2bf(pa.single[e]); continue; }
    e -= n0;
    if (e < n1){
      int j8 = e & 7, l = (e >> 3) & 63, ctt = e >> 9;
      int ct = ctt % CT1, t = ctt / CT1;
      int k = t * 32 + ((l >> 4) << 3) + j8;
      int col = (ct << 4) + (l & 15);
      float v;
      if (col < 1152){
        const float* W = (col < 384) ? pa.Wq : (col < 768 ? pa.Wk : pa.Wv);
        v = W[k * 384 + (col % 384)];
      } else {
        int c2 = col - 1152;
        const float* W = (c2 < 144) ? pa.Wqp : (c2 < 288 ? pa.Wkp : pa.Wvp);
        v = W[k * 144 + (c2 % 144)];
      }
      pa.wcat[e] = f2bf(v); continue;
    }
    e -= n1;
    {
      int col = e; float v;
      if (col < 1152){
        const float* bb = (col < 384) ? pa.bq : (col < 768 ? pa.bk : pa.bv);
        v = bb[col % 384];
      } else {
        int c2 = col - 1152;
        const float* bb = (c2 < 144) ? pa.bqp : (c2 < 288 ? pa.bkp : pa.bvp);
        v = bb[c2 % 144];
      }
      pa.bcat[col] = v;
    }
  }
}

// ------------------------------------------------------------ generic MFMA GEMM
__global__ __launch_bounds__(256) void gemm_mfma(
    const unsigned short* __restrict__ A, int lda, int ksteps,
    const unsigned short* __restrict__ wfrag, int ct_total,
    const float* __restrict__ bias, float* __restrict__ outf, int ncols)
{
  int l = threadIdx.x & 63, w = threadIdx.x >> 6;
  int m0 = blockIdx.x * 64 + w * 16;
  const unsigned short* Ap = A + (long)(m0 + (l & 15)) * lda + ((l >> 4) << 3);
  int ct0 = blockIdx.y * 3;
  f32x4 acc0 = {0,0,0,0}, acc1 = {0,0,0,0}, acc2 = {0,0,0,0};
  for (int t = 0; t < ksteps; ++t){
    short8 a = *(const short8*)(Ap + t * 32);
    const unsigned short* wp_ = wfrag + ((long)(t * ct_total + ct0) * 64 + l) * 8;
    short8 b0 = *(const short8*)(wp_);
    short8 b1 = *(const short8*)(wp_ + 512);
    short8 b2 = *(const short8*)(wp_ + 1024);
    acc0 = __builtin_amdgcn_mfma_f32_16x16x32_bf16(a, b0, acc0, 0, 0, 0);
    acc1 = __builtin_amdgcn_mfma_f32_16x16x32_bf16(a, b1, acc1, 0, 0, 0);
    acc2 = __builtin_amdgcn_mfma_f32_16x16x32_bf16(a, b2, acc2, 0, 0, 0);
  }
  int rbase = m0 + ((l >> 4) << 2);
  int cb = blockIdx.y * 48 + (l & 15);
#pragma unroll
  for (int c = 0; c < 3; ++c){
    f32x4 ac = (c == 0) ? acc0 : (c == 1 ? acc1 : acc2);
    int col = cb + c * 16;
    float bb = bias[col];
#pragma unroll
    for (int r = 0; r < 4; ++r){
      long idx = (long)(rbase + r) * ncols + col;
      outf[idx] = ac[r] + bb;
    }
  }
}

// --------------------- megapack: bias MFMA interleaved with aux jobs
// bijective mapping over 9456 blocks: every 8th block (bid<9363) + tail 93 = aux
#define MEGA_T   9363
#define MEGA_GRID 9456
__global__ __launch_bounds__(256) void megapack_kernel(
    const float* __restrict__ pair, const float* __restrict__ Wpb,
    const float* __restrict__ bpb,
    const float* __restrict__ proj, const float* __restrict__ rot,
    const float* __restrict__ trans, const float* __restrict__ mask,
    const float* __restrict__ Wpo, const float* __restrict__ Wo,
    unsigned short* __restrict__ biasf,
    unsigned short* __restrict__ qf, unsigned short* __restrict__ kf,
    unsigned short* __restrict__ vf,
    float* __restrict__ q2h, float* __restrict__ k2h,
    unsigned short* __restrict__ wpof, unsigned short* __restrict__ wof,
    unsigned short* __restrict__ wppad)
{
  __shared__ float scal[3][32][32];
  __shared__ float praw[3][32][12];
  __shared__ float pg[3][32][12];
  __shared__ float rots[32][9];
  __shared__ float trs[32][3];
  __shared__ float msk[32];

  int bid = blockIdx.x;
  int tid = threadIdx.x;
  bool isaux; int jid;
  if (bid < MEGA_T){
    if ((bid & 7) == 0){ isaux = true; jid = bid >> 3; }
    else { isaux = false; jid = bid - (bid >> 3) - 1; }
  } else { isaux = true; jid = 1171 + (bid - MEGA_T); }

  if (!isaux){
    // ---- pair-bias MFMA block (HBM-bound)
    int l = tid & 63, w = tid >> 6;
    long m0 = (long)jid * 64 + w * 16;
    long m = m0 + (l & 15);
    int kb = (l >> 4) << 3;
    int col = l & 15;
    short8 bf[4];
#pragma unroll
    for (int t = 0; t < 4; ++t){
#pragma unroll
      for (int j = 0; j < 8; ++j){
        int k = t * 32 + kb + j;
        float v = (col < 12) ? Wpb[k * 12 + col] : 0.f;
        bf[t][j] = (short)f2bf(v);
      }
    }
    const float* pr = pair + m * 128 + kb;
    f32x4 acc = {0,0,0,0};
#pragma unroll
    for (int t = 0; t < 4; ++t){
      float4 x0 = *(const float4*)(pr + t * 32);
      float4 x1 = *(const float4*)(pr + t * 32 + 4);
      short8 a;
      a[0] = (short)f2bf(x0.x); a[1] = (short)f2bf(x0.y);
      a[2] = (short)f2bf(x0.z); a[3] = (short)f2bf(x0.w);
      a[4] = (short)f2bf(x1.x); a[5] = (short)f2bf(x1.y);
      a[6] = (short)f2bf(x1.z); a[7] = (short)f2bf(x1.w);
      acc = __builtin_amdgcn_mfma_f32_16x16x32_bf16(a, bf[t], acc, 0, 0, 0);
    }
    int h = col;
    if (h < 12){
      long mr = m0 + ((l >> 4) << 2);
      int b  = (int)(mr >> 18);
      int i  = (int)((mr >> 9) & 511);
      int j  = (int)(mr & 511);
      int jt = j >> 5, f = (j >> 4) & 1, g2 = (j >> 2) & 3;
      int qt = i >> 4, q = i & 15;
      float bb = bpb[h];
      long e16 = (((((long)((b * 12 + h) * 16 + jt) * 32 + qt) * 2 + f) * 64) + (g2 * 16 + q)) * 4;
      uint2 wv; wv.x = pack2(acc[0] + bb, acc[1] + bb); wv.y = pack2(acc[2] + bb, acc[3] + bb);
      *(uint2*)(biasf + e16) = wv;
    }
    return;
  }

  // ---- aux jobs
  if (jid < 384){
    // LDS-staged q/k/v pack for (b, h, 32-row tile)
    int b = jid / 192, rem = jid % 192;
    int h = rem >> 4, rt = rem & 15;
    int j0 = rt * 32;
    int bn0 = b * 512 + j0;
    int bh = b * 12 + h;

    for (int idx = tid; idx < 3072; idx += 256){
      int a = idx >> 10, row = (idx >> 5) & 31, c = idx & 31;
      scal[a][row][c] = proj[(long)(bn0 + row) * NC1 + a * 384 + h * 32 + c];
    }
    for (int idx = tid; idx < 1152; idx += 256){
      int a = idx / 384, rr = idx % 384, row = rr / 12, pe = rr % 12;
      praw[a][row][pe] = proj[(long)(bn0 + row) * NC1 + 1152 + a * 144 + h * 12 + pe];
    }
    for (int idx = tid; idx < 288; idx += 256) rots[idx / 9][idx % 9] = rot[(long)(bn0 + idx / 9) * 9 + idx % 9];
    for (int idx = tid; idx < 96; idx += 256) trs[idx / 3][idx % 3] = trans[(long)(bn0 + idx / 3) * 3 + idx % 3];
    for (int idx = tid; idx < 32; idx += 256) msk[idx] = mask[bn0 + idx];
    __syncthreads();

    for (int idx = tid; idx < 1152; idx += 256){
      int a = idx / 384, rr = idx % 384, row = rr / 12, pe = rr % 12;
      int p = pe / 3, ee = pe % 3;
      pg[a][row][pe] = praw[a][row][p * 3] * rots[row][ee]
                     + praw[a][row][p * 3 + 1] * rots[row][3 + ee]
                     + praw[a][row][p * 3 + 2] * rots[row][6 + ee] + trs[row][ee];
    }
    __syncthreads();

    // q2h/k2h with mask fold
    for (int idx = tid; idx < 64; idx += 256){
      int a = idx >> 5, row = idx & 31;
      float s2 = 0.f;
#pragma unroll
      for (int pe = 0; pe < 12; ++pe){ float g = pg[a][row][pe]; s2 += g * g; }
      float mv = msk[row];
      float rres = -0.5f * SCALE * s2 + (mv != 0.f ? 0.f : -2e9f);
      (a ? k2h : q2h)[(long)bh * 512 + j0 + row] = rres;
    }

    // qf/kf fragments (2048 u32)
    for (int idx = tid; idx < 2048; idx += 256){
      int a = idx >> 10, r = idx & 1023;
      int jjp = r & 3, l = (r >> 2) & 63, ks = (r >> 8) & 1, sub = r >> 9;
      int row = sub * 16 + (l & 15);
      int kk = ks * 32 + ((l >> 4) << 3) + jjp * 2;
      int k1 = kk + 1;
      float v0 = (kk < 32) ? scal[a][row][kk] : (kk < 44 ? pg[a][row][kk - 32] : 0.f);
      float v1 = (k1 < 32) ? scal[a][row][k1] : (k1 < 44 ? pg[a][row][k1 - 32] : 0.f);
      if (a == 0){ v0 *= SCALE; v1 *= SCALE; }
      unsigned* dst = (unsigned*)(a ? kf : qf);
      dst[((((long)bh * 32 + rt * 2 + sub) * 2 + ks) * 64 + l) * 4 + jjp] = pack2(v0, v1);
    }

    // vf fragments (768 u32); this 32-row tile IS v-tile jt=rt
    for (int idx = tid; idx < 768; idx += 256){
      int jjp = idx & 3, l = (idx >> 2) & 63, cf = idx >> 8;
      int c = cf * 16 + (l & 15);
      int j = ((l >> 4) << 3) + jjp * 2;
      float v0 = (c < 32) ? scal[2][j][c]     : (c < 44 ? pg[2][j][c - 32]     : 0.f);
      float v1 = (c < 32) ? scal[2][j + 1][c] : (c < 44 ? pg[2][j + 1][c - 32] : 0.f);
      ((unsigned*)vf)[(((long)bh * 16 + rt) * 3 + cf) * 256 + l * 4 + jjp] = pack2(v0, v1);
    }
    return;
  }
  if (jid < 624){
    int e = (jid - 384) * 256 + tid;           // 61440 wpof elems
    int j8 = e & 7, l = (e >> 3) & 63, ctt = e >> 9;
    int ct = ctt % 24, t = ctt / 24;
    int k = t * 32 + ((l >> 4) << 3) + j8;
    int col = (ct << 4) + (l & 15);
    wpof[e] = (k < 144) ? f2bf(Wpo[k * 384 + col]) : (unsigned short)0;
    return;
  }
  if (jid < 1200){
    int e = (jid - 624) * 256 + tid;           // 147456 wof elems
    int j8 = e & 7, l = (e >> 3) & 63, ctt = e >> 9;
    int ct = ctt % 24, t = ctt / 24;
    int k = t * 32 + ((l >> 4) << 3) + j8;
    int col = (ct << 4) + (l & 15);
    wof[e] = f2bf(Wo[k * 384 + col]);
    return;
  }
  {
    int e = (jid - 1200) * 256 + tid;          // 16384 pad elems
    int row = e >> 4, c = e & 15;
    wppad[row * 160 + 144 + c] = 0;
  }
}

// ----------------------------- flash-style MFMA attention: 1 wave / 16 q-rows
__global__ __launch_bounds__(64) void attn2_kernel(
    const unsigned short* __restrict__ qf, const unsigned short* __restrict__ kf,
    const unsigned short* __restrict__ vf, const unsigned short* __restrict__ biasf,
    const float* __restrict__ q2h, const float* __restrict__ k2h,
    float* __restrict__ wsout, unsigned short* __restrict__ wpout)
{
  __shared__ unsigned short pls[2][16][40];
  int l = threadIdx.x;
  int qt = blockIdx.x, h = blockIdx.y, b = blockIdx.z;
  int bh = b * 12 + h;
  int g = l >> 4, q_ = l & 15;

  const short8* qp = (const short8*)(qf + (((long)(bh * 32 + qt) * 2) * 64 + l) * 8);
  short8 qA = qp[0], qB = qp[64];
  float cq = q2h[(long)bh * 512 + qt * 16 + q_];

  float m = -1e30f, ls = 0.f;
  f32x4 o0 = {0,0,0,0}, o1 = {0,0,0,0}, o2 = {0,0,0,0};
  const f32x4 z4 = {0,0,0,0};

#pragma unroll 2
  for (int jt = 0; jt < 16; ++jt){
    const short8* kp = (const short8*)(kf + (((long)(bh * 32 + jt * 2) * 2) * 64 + l) * 8);
    short8 k00 = kp[0], k01 = kp[64], k10 = kp[128], k11 = kp[192];
    f32x4 s0 = __builtin_amdgcn_mfma_f32_16x16x32_bf16(k00, qA, z4, 0, 0, 0);
    s0 = __builtin_amdgcn_mfma_f32_16x16x32_bf16(k01, qB, s0, 0, 0, 0);
    f32x4 s1 = __builtin_amdgcn_mfma_f32_16x16x32_bf16(k10, qA, z4, 0, 0, 0);
    s1 = __builtin_amdgcn_mfma_f32_16x16x32_bf16(k11, qB, s1, 0, 0, 0);

    const uint2* bp = (const uint2*)(biasf + ((((long)(bh * 16 + jt) * 32 + qt) * 2) * 64) * 4);
    uint2 bb0 = bp[l], bb1 = bp[64 + l];
    const float4* k2p = (const float4*)(k2h + (long)bh * 512 + jt * 32);
    float4 ck0 = k2p[g], ck1 = k2p[4 + g];

    s0[0] += bf_lo(bb0.x) + cq + ck0.x;
    s0[1] += bf_hi(bb0.x) + cq + ck0.y;
    s0[2] += bf_lo(bb0.y) + cq + ck0.z;
    s0[3] += bf_hi(bb0.y) + cq + ck0.w;
    s1[0] += bf_lo(bb1.x) + cq + ck1.x;
    s1[1] += bf_hi(bb1.x) + cq + ck1.y;
    s1[2] += bf_lo(bb1.y) + cq + ck1.z;
    s1[3] += bf_hi(bb1.y) + cq + ck1.w;

    float tm = fmaxf(fmaxf(fmaxf(s0[0], s0[1]), fmaxf(s0[2], s0[3])),
                     fmaxf(fmaxf(s1[0], s1[1]), fmaxf(s1[2], s1[3])));
    tm = fmaxf(tm, __shfl_xor(tm, 16));
    tm = fmaxf(tm, __shfl_xor(tm, 32));
    float mn = fmaxf(m, tm);
    float alpha = __expf(m - mn);
    f32x4 p0, p1;
    float ts = 0.f;
#pragma unroll
    for (int r = 0; r < 4; ++r){ p0[r] = __expf(s0[r] - mn); ts += p0[r]; }
#pragma unroll
    for (int r = 0; r < 4; ++r){ p1[r] = __expf(s1[r] - mn); ts += p1[r]; }
    ts += __shfl_xor(ts, 16);
    ts += __shfl_xor(ts, 32);
    ls = ls * alpha + ts; m = mn;

    f32x4 av;
#pragma unroll
    for (int r = 0; r < 4; ++r) av[r] = __shfl(alpha, g * 4 + r);
#pragma unroll
    for (int r = 0; r < 4; ++r){ o0[r] *= av[r]; o1[r] *= av[r]; o2[r] *= av[r]; }

    uint2 w0; w0.x = pack2(p0[0], p0[1]); w0.y = pack2(p0[2], p0[3]);
    uint2 w1; w1.x = pack2(p1[0], p1[1]); w1.y = pack2(p1[2], p1[3]);
    int bufi = jt & 1;
    *(uint2*)&pls[bufi][q_][g * 4]      = w0;
    *(uint2*)&pls[bufi][q_][16 + g * 4] = w1;
    short8 pa = *(const short8*)&pls[bufi][q_][g * 8];

    const short8* vp = (const short8*)(vf + (((long)(bh * 16 + jt) * 3) * 64 + l) * 8);
    short8 v0 = vp[0], v1 = vp[64], v2 = vp[128];
    o0 = __builtin_amdgcn_mfma_f32_16x16x32_bf16(pa, v0, o0, 0, 0, 0);
    o1 = __builtin_amdgcn_mfma_f32_16x16x32_bf16(pa, v1, o1, 0, 0, 0);
    o2 = __builtin_amdgcn_mfma_f32_16x16x32_bf16(pa, v2, o2, 0, 0, 0);
  }

  float inv = 1.f / ls;
  f32x4 iv;
#pragma unroll
  for (int r = 0; r < 4; ++r) iv[r] = __shfl(inv, g * 4 + r);
#pragma unroll
  for (int r = 0; r < 4; ++r){
    long bn = (long)b * 512 + qt * 16 + g * 4 + r;
    wsout[bn * 384 + h * 32 + q_]      = o0[r] * iv[r];
    wsout[bn * 384 + h * 32 + 16 + q_] = o1[r] * iv[r];
    if (q_ < 12) wpout[bn * 160 + h * 12 + q_] = f2bf(o2[r] * iv[r]);
  }
}

// --------- tail: 64 blocks x 16 rows; 4 waves split the 24 col-tiles (6 each)
__global__ __launch_bounds__(256) void tail_kernel(
    const unsigned short* __restrict__ wpbuf, const unsigned short* __restrict__ wpof,
    const float* __restrict__ bpo, const float* __restrict__ wso,
    const unsigned short* __restrict__ wof, const float* __restrict__ bo,
    const float* __restrict__ single, const float* __restrict__ ln_g,
    const float* __restrict__ ln_b, float* __restrict__ out)
{
  __shared__ unsigned short t1s[16][392];
  __shared__ float redS[4][16], redQ[4][16];
  int l = threadIdx.x & 63, w = threadIdx.x >> 6;
  int m0 = blockIdx.x * 16;
  int rb = (l >> 4) << 2;                 // local row base (0,4,8,12)
  int arow = m0 + (l & 15);               // A row this lane serves

  // stage 1: t1 = wp @ Wpo + bpo + wso   (this wave: cts w*6 .. w*6+5)
  {
    short8 awp[5];
    const unsigned short* Ap = wpbuf + (long)arow * 160 + ((l >> 4) << 3);
#pragma unroll
    for (int t = 0; t < 5; ++t) awp[t] = *(const short8*)(Ap + t * 32);
#pragma unroll
    for (int c6 = 0; c6 < 6; ++c6){
      int ct = w * 6 + c6;
      f32x4 acc = {0,0,0,0};
#pragma unroll
      for (int t = 0; t < 5; ++t){
        short8 bfr = *(const short8*)(wpof + ((long)(t * 24 + ct) * 64 + l) * 8);
        acc = __builtin_amdgcn_mfma_f32_16x16x32_bf16(awp[t], bfr, acc, 0, 0, 0);
      }
      int col = ct * 16 + (l & 15);
      float bb = bpo[col];
#pragma unroll
      for (int r = 0; r < 4; ++r){
        float v = acc[r] + bb + wso[(long)(m0 + rb + r) * 384 + col];
        t1s[rb + r][col] = f2bf(v);
      }
    }
  }
  __syncthreads();

  // stage 2: x = t1 @ Wo + bo + single; partial LN sums
  short8 a2[12];
  {
    int lr = l & 15;
#pragma unroll
    for (int t = 0; t < 12; ++t)
      a2[t] = *(const short8*)&t1s[lr][t * 32 + ((l >> 4) << 3)];
  }
  f32x4 xa[6];
  float s1[4] = {0,0,0,0}, s2[4] = {0,0,0,0};
#pragma unroll
  for (int c6 = 0; c6 < 6; ++c6){
    int ct = w * 6 + c6;
    f32x4 acc = {0,0,0,0};
#pragma unroll
    for (int t = 0; t < 12; ++t){
      short8 bfr = *(const short8*)(wof + ((long)(t * 24 + ct) * 64 + l) * 8);
      acc = __builtin_amdgcn_mfma_f32_16x16x32_bf16(a2[t], bfr, acc, 0, 0, 0);
    }
    int col = ct * 16 + (l & 15);
    float bb = bo[col];
#pragma unroll
    for (int r = 0; r < 4; ++r){
      float v = acc[r] + bb + single[(long)(m0 + rb + r) * 384 + col];
      acc[r] = v; s1[r] += v; s2[r] += v * v;
    }
    xa[c6] = acc;
  }
#pragma unroll
  for (int off = 1; off < 16; off <<= 1){
#pragma unroll
    for (int r = 0; r < 4; ++r){
      s1[r] += __shfl_xor(s1[r], off);
      s2[r] += __shfl_xor(s2[r], off);
    }
  }
  if ((l & 15) == 0){
#pragma unroll
    for (int r = 0; r < 4; ++r){ redS[w][rb + r] = s1[r]; redQ[w][rb + r] = s2[r]; }
  }
  __syncthreads();
  float mu[4], inv[4];
#pragma unroll
  for (int r = 0; r < 4; ++r){
    float ts = redS[0][rb + r] + redS[1][rb + r] + redS[2][rb + r] + redS[3][rb + r];
    float tq = redQ[0][rb + r] + redQ[1][rb + r] + redQ[2][rb + r] + redQ[3][rb + r];
    mu[r] = ts * (1.f / 384.f);
    float var = tq * (1.f / 384.f) - mu[r] * mu[r];
    inv[r] = rsqrtf(var + 1e-5f);
  }
#pragma unroll
  for (int c6 = 0; c6 < 6; ++c6){
    int ct = w * 6 + c6;
    int col = ct * 16 + (l & 15);
    float g = ln_g[col], bt = ln_b[col];
#pragma unroll
    for (int r = 0; r < 4; ++r)
      out[(long)(m0 + rb + r) * 384 + col] = (xa[c6][r] - mu[r]) * inv[r] * g + bt;
  }
}

// -------------------------------------------------------------------- launcher
extern "C" void kernel_launch(void* const* d_in, const int* in_sizes, int n_in,
                              void* d_out, int out_size, void* d_ws, size_t ws_size,
                              hipStream_t stream)
{
  const float* single = (const float*)d_in[0];
  const float* pair   = (const float*)d_in[1];
  const float* rot    = (const float*)d_in[2];
  const float* trans  = (const float*)d_in[3];
  const float* mask   = (const float*)d_in[4];
  const float* Wq  = (const float*)d_in[5];  const float* bq  = (const float*)d_in[6];
  const float* Wk  = (const float*)d_in[7];  const float* bk  = (const float*)d_in[8];
  const float* Wv  = (const float*)d_in[9];  const float* bv  = (const float*)d_in[10];
  const float* Wpb = (const float*)d_in[11]; const float* bpb = (const float*)d_in[12];
  const float* Wqp = (const float*)d_in[13]; const float* bqp = (const float*)d_in[14];
  const float* Wkp = (const float*)d_in[15]; const float* bkp = (const float*)d_in[16];
  const float* Wvp = (const float*)d_in[17]; const float* bvp = (const float*)d_in[18];
  const float* Wo  = (const float*)d_in[19]; const float* bo  = (const float*)d_in[20];
  const float* Wpo = (const float*)d_in[21]; const float* bpo = (const float*)d_in[22];
  const float* ln_g = (const float*)d_in[23]; const float* ln_b = (const float*)d_in[24];

  char* wsb = (char*)d_ws;
  size_t off = 0;
  auto alloc = [&](size_t bytes) -> void* {
    void* p = wsb + off; off += (bytes + 255) & ~(size_t)255; return p;
  };
  unsigned short* sbf  = (unsigned short*)alloc((size_t)BN * Cc * 2);
  unsigned short* wcat = (unsigned short*)alloc((size_t)12 * CT1 * 512 * 2);
  unsigned short* wpof = (unsigned short*)alloc((size_t)5 * 24 * 512 * 2);
  unsigned short* wof  = (unsigned short*)alloc((size_t)12 * 24 * 512 * 2);
  float* bcat  = (float*)alloc(NC1 * 4);
  float* proj  = (float*)alloc((size_t)BN * NC1 * 4);
  unsigned short* biasf = (unsigned short*)alloc((size_t)Bb * Hh * Nn * Nn * 2);
  unsigned short* qfragb = (unsigned short*)alloc((size_t)786432 * 2);
  unsigned short* kfragb = (unsigned short*)alloc((size_t)786432 * 2);
  unsigned short* vfragb = (unsigned short*)alloc((size_t)589824 * 2);
  float* q2hb  = (float*)alloc((size_t)12288 * 4);
  float* k2hb  = (float*)alloc((size_t)12288 * 4);
  float* wso   = (float*)alloc((size_t)BN * 384 * 4);
  unsigned short* wpbuf = (unsigned short*)alloc((size_t)BN * 160 * 2);
  if (off > ws_size) return;

  PrepArgs pa;
  pa.single = single; pa.Wq = Wq; pa.Wk = Wk; pa.Wv = Wv;
  pa.Wqp = Wqp; pa.Wkp = Wkp; pa.Wvp = Wvp;
  pa.bq = bq; pa.bk = bk; pa.bv = bv; pa.bqp = bqp; pa.bkp = bkp; pa.bvp = bvp;
  pa.sbf = sbf; pa.wcat = wcat; pa.bcat = bcat;

  prep_kernel<<<512, 256, 0, stream>>>(pa);
  gemm_mfma<<<dim3(16, 33), 256, 0, stream>>>(sbf, Cc, 12, wcat, CT1, bcat, proj, NC1);
  megapack_kernel<<<MEGA_GRID, 256, 0, stream>>>(
      pair, Wpb, bpb, proj, rot, trans, mask, Wpo, Wo,
      biasf, qfragb, kfragb, vfragb, q2hb, k2hb, wpof, wof, wpbuf);
  attn2_kernel<<<dim3(32, 12, 2), 64, 0, stream>>>(qfragb, kfragb, vfragb, biasf,
                                                   q2hb, k2hb, wso, wpbuf);
  tail_kernel<<<64, 256, 0, stream>>>(wpbuf, wpof, bpo, wso, wof, bo,
                                      single, ln_g, ln_b, (float*)d_out);
}

// Round 5
// 117.253 us; speedup vs baseline: 2.3451x; 1.0824x over previous
//
#include <hip/hip_runtime.h>
#include <hip/hip_bf16.h>

// Problem constants
#define Bb   2
#define Nn   512
#define Cc   384
#define Hh   12
#define Pp   4
#define DPp  128
#define CHh  32
#define BN   1024          // B*N
#define NC1  1584          // 3*384 + 3*144 concatenated proj cols
#define CT1  99            // 1584/16 col-tiles
#define SCALE 0.17677669529663687f   // 32^-0.5

typedef __attribute__((ext_vector_type(8))) short short8;
typedef __attribute__((ext_vector_type(4))) float f32x4;

__device__ __forceinline__ unsigned short f2bf(float f){
  union { float f; unsigned u; } v; v.f = f;
  unsigned u = v.u;
  unsigned r = u + 0x7fffu + ((u >> 16) & 1u);
  return (unsigned short)(r >> 16);
}
__device__ __forceinline__ float bf_lo(unsigned u){ union{unsigned u; float f;} v; v.u = u << 16; return v.f; }
__device__ __forceinline__ float bf_hi(unsigned u){ union{unsigned u; float f;} v; v.u = u & 0xffff0000u; return v.f; }
__device__ __forceinline__ unsigned pack2(float a, float b){
  return (unsigned)f2bf(a) | ((unsigned)f2bf(b) << 16);
}

// ----------------------------------------------- prep: sbf + wcat + bcat only
struct PrepArgs {
  const float *single, *Wq, *Wk, *Wv, *Wqp, *Wkp, *Wvp;
  const float *bq, *bk, *bv, *bqp, *bkp, *bvp;
  unsigned short *sbf, *wcat;
  float *bcat;
};

__global__ void prep_kernel(PrepArgs pa){
  const int n0 = BN * Cc;
  const int n1 = 12 * CT1 * 512;
  const int n4 = NC1;
  const int total = n0 + n1 + n4;
  for (int i = blockIdx.x * blockDim.x + threadIdx.x; i < total; i += gridDim.x * blockDim.x){
    int e = i;
    if (e < n0){ pa.sbf[e] = f2bf(pa.single[e]); continue; }
    e -= n0;
    if (e < n1){
      int j8 = e & 7, l = (e >> 3) & 63, ctt = e >> 9;
      int ct = ctt % CT1, t = ctt / CT1;
      int k = t * 32 + ((l >> 4) << 3) + j8;
      int col = (ct << 4) + (l & 15);
      float v;
      if (col < 1152){
        const float* W = (col < 384) ? pa.Wq : (col < 768 ? pa.Wk : pa.Wv);
        v = W[k * 384 + (col % 384)];
      } else {
        int c2 = col - 1152;
        const float* W = (c2 < 144) ? pa.Wqp : (c2 < 288 ? pa.Wkp : pa.Wvp);
        v = W[k * 144 + (c2 % 144)];
      }
      pa.wcat[e] = f2bf(v); continue;
    }
    e -= n1;
    {
      int col = e; float v;
      if (col < 1152){
        const float* bb = (col < 384) ? pa.bq : (col < 768 ? pa.bk : pa.bv);
        v = bb[col % 384];
      } else {
        int c2 = col - 1152;
        const float* bb = (c2 < 144) ? pa.bqp : (c2 < 288 ? pa.bkp : pa.bvp);
        v = bb[c2 % 144];
      }
      pa.bcat[col] = v;
    }
  }
}

// ------------------------------------------------------------ generic MFMA GEMM
__global__ __launch_bounds__(256) void gemm_mfma(
    const unsigned short* __restrict__ A, int lda, int ksteps,
    const unsigned short* __restrict__ wfrag, int ct_total,
    const float* __restrict__ bias, float* __restrict__ outf, int ncols)
{
  int l = threadIdx.x & 63, w = threadIdx.x >> 6;
  int m0 = blockIdx.x * 64 + w * 16;
  const unsigned short* Ap = A + (long)(m0 + (l & 15)) * lda + ((l >> 4) << 3);
  int ct0 = blockIdx.y * 3;
  f32x4 acc0 = {0,0,0,0}, acc1 = {0,0,0,0}, acc2 = {0,0,0,0};
  for (int t = 0; t < ksteps; ++t){
    short8 a = *(const short8*)(Ap + t * 32);
    const unsigned short* wp_ = wfrag + ((long)(t * ct_total + ct0) * 64 + l) * 8;
    short8 b0 = *(const short8*)(wp_);
    short8 b1 = *(const short8*)(wp_ + 512);
    short8 b2 = *(const short8*)(wp_ + 1024);
    acc0 = __builtin_amdgcn_mfma_f32_16x16x32_bf16(a, b0, acc0, 0, 0, 0);
    acc1 = __builtin_amdgcn_mfma_f32_16x16x32_bf16(a, b1, acc1, 0, 0, 0);
    acc2 = __builtin_amdgcn_mfma_f32_16x16x32_bf16(a, b2, acc2, 0, 0, 0);
  }
  int rbase = m0 + ((l >> 4) << 2);
  int cb = blockIdx.y * 48 + (l & 15);
#pragma unroll
  for (int c = 0; c < 3; ++c){
    f32x4 ac = (c == 0) ? acc0 : (c == 1 ? acc1 : acc2);
    int col = cb + c * 16;
    float bb = bias[col];
#pragma unroll
    for (int r = 0; r < 4; ++r){
      long idx = (long)(rbase + r) * ncols + col;
      outf[idx] = ac[r] + bb;
    }
  }
}

// --------------------- megapack: bias MFMA interleaved with aux jobs
#define MEGA_T   9363
#define MEGA_GRID 9456
__global__ __launch_bounds__(256) void megapack_kernel(
    const float* __restrict__ pair, const float* __restrict__ Wpb,
    const float* __restrict__ bpb,
    const float* __restrict__ proj, const float* __restrict__ rot,
    const float* __restrict__ trans, const float* __restrict__ mask,
    const float* __restrict__ Wpo, const float* __restrict__ Wo,
    unsigned short* __restrict__ biasf,
    unsigned short* __restrict__ qf, unsigned short* __restrict__ kf,
    unsigned short* __restrict__ vf,
    float* __restrict__ q2h, float* __restrict__ k2h,
    unsigned short* __restrict__ wpof, unsigned short* __restrict__ wof,
    unsigned short* __restrict__ wppad)
{
  __shared__ float scal[3][32][32];
  __shared__ float praw[3][32][12];
  __shared__ float pg[3][32][12];
  __shared__ float rots[32][9];
  __shared__ float trs[32][3];
  __shared__ float msk[32];

  int bid = blockIdx.x;
  int tid = threadIdx.x;
  bool isaux; int jid;
  if (bid < MEGA_T){
    if ((bid & 7) == 0){ isaux = true; jid = bid >> 3; }
    else { isaux = false; jid = bid - (bid >> 3) - 1; }
  } else { isaux = true; jid = 1171 + (bid - MEGA_T); }

  if (!isaux){
    int l = tid & 63, w = tid >> 6;
    long m0 = (long)jid * 64 + w * 16;
    long m = m0 + (l & 15);
    int kb = (l >> 4) << 3;
    int col = l & 15;
    short8 bf[4];
#pragma unroll
    for (int t = 0; t < 4; ++t){
#pragma unroll
      for (int j = 0; j < 8; ++j){
        int k = t * 32 + kb + j;
        float v = (col < 12) ? Wpb[k * 12 + col] : 0.f;
        bf[t][j] = (short)f2bf(v);
      }
    }
    const float* pr = pair + m * 128 + kb;
    f32x4 acc = {0,0,0,0};
#pragma unroll
    for (int t = 0; t < 4; ++t){
      float4 x0 = *(const float4*)(pr + t * 32);
      float4 x1 = *(const float4*)(pr + t * 32 + 4);
      short8 a;
      a[0] = (short)f2bf(x0.x); a[1] = (short)f2bf(x0.y);
      a[2] = (short)f2bf(x0.z); a[3] = (short)f2bf(x0.w);
      a[4] = (short)f2bf(x1.x); a[5] = (short)f2bf(x1.y);
      a[6] = (short)f2bf(x1.z); a[7] = (short)f2bf(x1.w);
      acc = __builtin_amdgcn_mfma_f32_16x16x32_bf16(a, bf[t], acc, 0, 0, 0);
    }
    int h = col;
    if (h < 12){
      long mr = m0 + ((l >> 4) << 2);
      int b  = (int)(mr >> 18);
      int i  = (int)((mr >> 9) & 511);
      int j  = (int)(mr & 511);
      int jt = j >> 5, f = (j >> 4) & 1, g2 = (j >> 2) & 3;
      int qt = i >> 4, q = i & 15;
      float bb = bpb[h];
      long e16 = (((((long)((b * 12 + h) * 16 + jt) * 32 + qt) * 2 + f) * 64) + (g2 * 16 + q)) * 4;
      uint2 wv; wv.x = pack2(acc[0] + bb, acc[1] + bb); wv.y = pack2(acc[2] + bb, acc[3] + bb);
      *(uint2*)(biasf + e16) = wv;
    }
    return;
  }

  if (jid < 384){
    int b = jid / 192, rem = jid % 192;
    int h = rem >> 4, rt = rem & 15;
    int j0 = rt * 32;
    int bn0 = b * 512 + j0;
    int bh = b * 12 + h;

    for (int idx = tid; idx < 3072; idx += 256){
      int a = idx >> 10, row = (idx >> 5) & 31, c = idx & 31;
      scal[a][row][c] = proj[(long)(bn0 + row) * NC1 + a * 384 + h * 32 + c];
    }
    for (int idx = tid; idx < 1152; idx += 256){
      int a = idx / 384, rr = idx % 384, row = rr / 12, pe = rr % 12;
      praw[a][row][pe] = proj[(long)(bn0 + row) * NC1 + 1152 + a * 144 + h * 12 + pe];
    }
    for (int idx = tid; idx < 288; idx += 256) rots[idx / 9][idx % 9] = rot[(long)(bn0 + idx / 9) * 9 + idx % 9];
    for (int idx = tid; idx < 96; idx += 256) trs[idx / 3][idx % 3] = trans[(long)(bn0 + idx / 3) * 3 + idx % 3];
    for (int idx = tid; idx < 32; idx += 256) msk[idx] = mask[bn0 + idx];
    __syncthreads();

    for (int idx = tid; idx < 1152; idx += 256){
      int a = idx / 384, rr = idx % 384, row = rr / 12, pe = rr % 12;
      int p = pe / 3, ee = pe % 3;
      pg[a][row][pe] = praw[a][row][p * 3] * rots[row][ee]
                     + praw[a][row][p * 3 + 1] * rots[row][3 + ee]
                     + praw[a][row][p * 3 + 2] * rots[row][6 + ee] + trs[row][ee];
    }
    __syncthreads();

    for (int idx = tid; idx < 64; idx += 256){
      int a = idx >> 5, row = idx & 31;
      float s2 = 0.f;
#pragma unroll
      for (int pe = 0; pe < 12; ++pe){ float g = pg[a][row][pe]; s2 += g * g; }
      float mv = msk[row];
      float rres = -0.5f * SCALE * s2 + (mv != 0.f ? 0.f : -2e9f);
      (a ? k2h : q2h)[(long)bh * 512 + j0 + row] = rres;
    }

    for (int idx = tid; idx < 2048; idx += 256){
      int a = idx >> 10, r = idx & 1023;
      int jjp = r & 3, l = (r >> 2) & 63, ks = (r >> 8) & 1, sub = r >> 9;
      int row = sub * 16 + (l & 15);
      int kk = ks * 32 + ((l >> 4) << 3) + jjp * 2;
      int k1 = kk + 1;
      float v0 = (kk < 32) ? scal[a][row][kk] : (kk < 44 ? pg[a][row][kk - 32] : 0.f);
      float v1 = (k1 < 32) ? scal[a][row][k1] : (k1 < 44 ? pg[a][row][k1 - 32] : 0.f);
      if (a == 0){ v0 *= SCALE; v1 *= SCALE; }
      unsigned* dst = (unsigned*)(a ? kf : qf);
      dst[((((long)bh * 32 + rt * 2 + sub) * 2 + ks) * 64 + l) * 4 + jjp] = pack2(v0, v1);
    }

    for (int idx = tid; idx < 768; idx += 256){
      int jjp = idx & 3, l = (idx >> 2) & 63, cf = idx >> 8;
      int c = cf * 16 + (l & 15);
      int j = ((l >> 4) << 3) + jjp * 2;
      float v0 = (c < 32) ? scal[2][j][c]     : (c < 44 ? pg[2][j][c - 32]     : 0.f);
      float v1 = (c < 32) ? scal[2][j + 1][c] : (c < 44 ? pg[2][j + 1][c - 32] : 0.f);
      ((unsigned*)vf)[(((long)bh * 16 + rt) * 3 + cf) * 256 + l * 4 + jjp] = pack2(v0, v1);
    }
    return;
  }
  if (jid < 624){
    int e = (jid - 384) * 256 + tid;
    int j8 = e & 7, l = (e >> 3) & 63, ctt = e >> 9;
    int ct = ctt % 24, t = ctt / 24;
    int k = t * 32 + ((l >> 4) << 3) + j8;
    int col = (ct << 4) + (l & 15);
    wpof[e] = (k < 144) ? f2bf(Wpo[k * 384 + col]) : (unsigned short)0;
    return;
  }
  if (jid < 1200){
    int e = (jid - 624) * 256 + tid;
    int j8 = e & 7, l = (e >> 3) & 63, ctt = e >> 9;
    int ct = ctt % 24, t = ctt / 24;
    int k = t * 32 + ((l >> 4) << 3) + j8;
    int col = (ct << 4) + (l & 15);
    wof[e] = f2bf(Wo[k * 384 + col]);
    return;
  }
  {
    int e = (jid - 1200) * 256 + tid;
    int row = e >> 4, c = e & 15;
    wppad[row * 160 + 144 + c] = 0;
  }
}

// ------------- flash MFMA attention: 4 waves/block, 4 j-tiles each + LDS merge
__global__ __launch_bounds__(256) void attn2_kernel(
    const unsigned short* __restrict__ qf, const unsigned short* __restrict__ kf,
    const unsigned short* __restrict__ vf, const unsigned short* __restrict__ biasf,
    const float* __restrict__ q2h, const float* __restrict__ k2h,
    float* __restrict__ wsout, unsigned short* __restrict__ wpout)
{
  __shared__ unsigned short pls[4][16][40];
  __shared__ float oW[4][3][64][4];
  __shared__ float mW[4][16], lsW[4][16];
  __shared__ float fW[4][16], linvS[16];

  int l = threadIdx.x & 63, w = threadIdx.x >> 6;
  int qt = blockIdx.x, h = blockIdx.y, b = blockIdx.z;
  int bh = b * 12 + h;
  int g = l >> 4, q_ = l & 15;

  const short8* qp = (const short8*)(qf + (((long)(bh * 32 + qt) * 2) * 64 + l) * 8);
  short8 qA = qp[0], qB = qp[64];
  float cq = q2h[(long)bh * 512 + qt * 16 + q_];

  float m = -1e30f, ls = 0.f;
  f32x4 o0 = {0,0,0,0}, o1 = {0,0,0,0}, o2 = {0,0,0,0};
  const f32x4 z4 = {0,0,0,0};

#pragma unroll
  for (int ji = 0; ji < 4; ++ji){
    int jt = w * 4 + ji;
    const short8* kp = (const short8*)(kf + (((long)(bh * 32 + jt * 2) * 2) * 64 + l) * 8);
    short8 k00 = kp[0], k01 = kp[64], k10 = kp[128], k11 = kp[192];
    f32x4 s0 = __builtin_amdgcn_mfma_f32_16x16x32_bf16(k00, qA, z4, 0, 0, 0);
    s0 = __builtin_amdgcn_mfma_f32_16x16x32_bf16(k01, qB, s0, 0, 0, 0);
    f32x4 s1 = __builtin_amdgcn_mfma_f32_16x16x32_bf16(k10, qA, z4, 0, 0, 0);
    s1 = __builtin_amdgcn_mfma_f32_16x16x32_bf16(k11, qB, s1, 0, 0, 0);

    const uint2* bp = (const uint2*)(biasf + ((((long)(bh * 16 + jt) * 32 + qt) * 2) * 64) * 4);
    uint2 bb0 = bp[l], bb1 = bp[64 + l];
    const float4* k2p = (const float4*)(k2h + (long)bh * 512 + jt * 32);
    float4 ck0 = k2p[g], ck1 = k2p[4 + g];

    s0[0] += bf_lo(bb0.x) + cq + ck0.x;
    s0[1] += bf_hi(bb0.x) + cq + ck0.y;
    s0[2] += bf_lo(bb0.y) + cq + ck0.z;
    s0[3] += bf_hi(bb0.y) + cq + ck0.w;
    s1[0] += bf_lo(bb1.x) + cq + ck1.x;
    s1[1] += bf_hi(bb1.x) + cq + ck1.y;
    s1[2] += bf_lo(bb1.y) + cq + ck1.z;
    s1[3] += bf_hi(bb1.y) + cq + ck1.w;

    float tm = fmaxf(fmaxf(fmaxf(s0[0], s0[1]), fmaxf(s0[2], s0[3])),
                     fmaxf(fmaxf(s1[0], s1[1]), fmaxf(s1[2], s1[3])));
    tm = fmaxf(tm, __shfl_xor(tm, 16));
    tm = fmaxf(tm, __shfl_xor(tm, 32));
    float mn = fmaxf(m, tm);
    float alpha = __expf(m - mn);
    f32x4 p0, p1;
    float ts = 0.f;
#pragma unroll
    for (int r = 0; r < 4; ++r){ p0[r] = __expf(s0[r] - mn); ts += p0[r]; }
#pragma unroll
    for (int r = 0; r < 4; ++r){ p1[r] = __expf(s1[r] - mn); ts += p1[r]; }
    ts += __shfl_xor(ts, 16);
    ts += __shfl_xor(ts, 32);
    ls = ls * alpha + ts; m = mn;

    f32x4 av;
#pragma unroll
    for (int r = 0; r < 4; ++r) av[r] = __shfl(alpha, g * 4 + r);
#pragma unroll
    for (int r = 0; r < 4; ++r){ o0[r] *= av[r]; o1[r] *= av[r]; o2[r] *= av[r]; }

    uint2 w0; w0.x = pack2(p0[0], p0[1]); w0.y = pack2(p0[2], p0[3]);
    uint2 w1; w1.x = pack2(p1[0], p1[1]); w1.y = pack2(p1[2], p1[3]);
    *(uint2*)&pls[w][q_][g * 4]      = w0;
    *(uint2*)&pls[w][q_][16 + g * 4] = w1;
    short8 pa = *(const short8*)&pls[w][q_][g * 8];

    const short8* vp = (const short8*)(vf + (((long)(bh * 16 + jt) * 3) * 64 + l) * 8);
    short8 v0 = vp[0], v1 = vp[64], v2 = vp[128];
    o0 = __builtin_amdgcn_mfma_f32_16x16x32_bf16(pa, v0, o0, 0, 0, 0);
    o1 = __builtin_amdgcn_mfma_f32_16x16x32_bf16(pa, v1, o1, 0, 0, 0);
    o2 = __builtin_amdgcn_mfma_f32_16x16x32_bf16(pa, v2, o2, 0, 0, 0);
  }

  // ---- cross-wave merge
  if (g == 0){ mW[w][q_] = m; lsW[w][q_] = ls; }
  *(f32x4*)&oW[w][0][l][0] = o0;
  *(f32x4*)&oW[w][1][l][0] = o1;
  *(f32x4*)&oW[w][2][l][0] = o2;
  __syncthreads();

  if (w == 0){
    float M = fmaxf(fmaxf(mW[0][q_], mW[1][q_]), fmaxf(mW[2][q_], mW[3][q_]));
    float f = __expf(mW[g][q_] - M);   // lane (g,q_) handles wave g
    fW[g][q_] = f;
    float lf = lsW[g][q_] * f;
    lf += __shfl_xor(lf, 16);
    lf += __shfl_xor(lf, 32);
    if (g == 0) linvS[q_] = 1.f / lf;
  }
  __syncthreads();

  if (w < 3){
    float fr[4][4];  // [vw][r]
    float li[4];
#pragma unroll
    for (int r = 0; r < 4; ++r){
      int q = g * 4 + r;
      li[r] = linvS[q];
#pragma unroll
      for (int vw = 0; vw < 4; ++vw) fr[vw][r] = fW[vw][q];
    }
    f32x4 sum = {0,0,0,0};
#pragma unroll
    for (int vw = 0; vw < 4; ++vw){
      f32x4 ov = *(const f32x4*)&oW[vw][w][l][0];
#pragma unroll
      for (int r = 0; r < 4; ++r) sum[r] += ov[r] * fr[vw][r];
    }
#pragma unroll
    for (int r = 0; r < 4; ++r){
      long bn = (long)b * 512 + qt * 16 + g * 4 + r;
      float val = sum[r] * li[r];
      if (w == 0)      wsout[bn * 384 + h * 32 + q_] = val;
      else if (w == 1) wsout[bn * 384 + h * 32 + 16 + q_] = val;
      else if (q_ < 12) wpout[bn * 160 + h * 12 + q_] = f2bf(val);
    }
  }
}

// --------- tail: 64 blocks x 16 rows; 4 waves split the 24 col-tiles (6 each)
__global__ __launch_bounds__(256) void tail_kernel(
    const unsigned short* __restrict__ wpbuf, const unsigned short* __restrict__ wpof,
    const float* __restrict__ bpo, const float* __restrict__ wso,
    const unsigned short* __restrict__ wof, const float* __restrict__ bo,
    const float* __restrict__ single, const float* __restrict__ ln_g,
    const float* __restrict__ ln_b, float* __restrict__ out)
{
  __shared__ unsigned short t1s[16][392];
  __shared__ float redS[4][16], redQ[4][16];
  int l = threadIdx.x & 63, w = threadIdx.x >> 6;
  int m0 = blockIdx.x * 16;
  int rb = (l >> 4) << 2;
  int arow = m0 + (l & 15);

  {
    short8 awp[5];
    const unsigned short* Ap = wpbuf + (long)arow * 160 + ((l >> 4) << 3);
#pragma unroll
    for (int t = 0; t < 5; ++t) awp[t] = *(const short8*)(Ap + t * 32);
#pragma unroll
    for (int c6 = 0; c6 < 6; ++c6){
      int ct = w * 6 + c6;
      f32x4 acc = {0,0,0,0};
#pragma unroll
      for (int t = 0; t < 5; ++t){
        short8 bfr = *(const short8*)(wpof + ((long)(t * 24 + ct) * 64 + l) * 8);
        acc = __builtin_amdgcn_mfma_f32_16x16x32_bf16(awp[t], bfr, acc, 0, 0, 0);
      }
      int col = ct * 16 + (l & 15);
      float bb = bpo[col];
#pragma unroll
      for (int r = 0; r < 4; ++r){
        float v = acc[r] + bb + wso[(long)(m0 + rb + r) * 384 + col];
        t1s[rb + r][col] = f2bf(v);
      }
    }
  }
  __syncthreads();

  short8 a2[12];
  {
    int lr = l & 15;
#pragma unroll
    for (int t = 0; t < 12; ++t)
      a2[t] = *(const short8*)&t1s[lr][t * 32 + ((l >> 4) << 3)];
  }
  f32x4 xa[6];
  float s1[4] = {0,0,0,0}, s2[4] = {0,0,0,0};
#pragma unroll
  for (int c6 = 0; c6 < 6; ++c6){
    int ct = w * 6 + c6;
    f32x4 acc = {0,0,0,0};
#pragma unroll
    for (int t = 0; t < 12; ++t){
      short8 bfr = *(const short8*)(wof + ((long)(t * 24 + ct) * 64 + l) * 8);
      acc = __builtin_amdgcn_mfma_f32_16x16x32_bf16(a2[t], bfr, acc, 0, 0, 0);
    }
    int col = ct * 16 + (l & 15);
    float bb = bo[col];
#pragma unroll
    for (int r = 0; r < 4; ++r){
      float v = acc[r] + bb + single[(long)(m0 + rb + r) * 384 + col];
      acc[r] = v; s1[r] += v; s2[r] += v * v;
    }
    xa[c6] = acc;
  }
#pragma unroll
  for (int off = 1; off < 16; off <<= 1){
#pragma unroll
    for (int r = 0; r < 4; ++r){
      s1[r] += __shfl_xor(s1[r], off);
      s2[r] += __shfl_xor(s2[r], off);
    }
  }
  if ((l & 15) == 0){
#pragma unroll
    for (int r = 0; r < 4; ++r){ redS[w][rb + r] = s1[r]; redQ[w][rb + r] = s2[r]; }
  }
  __syncthreads();
  float mu[4], inv[4];
#pragma unroll
  for (int r = 0; r < 4; ++r){
    float ts = redS[0][rb + r] + redS[1][rb + r] + redS[2][rb + r] + redS[3][rb + r];
    float tq = redQ[0][rb + r] + redQ[1][rb + r] + redQ[2][rb + r] + redQ[3][rb + r];
    mu[r] = ts * (1.f / 384.f);
    float var = tq * (1.f / 384.f) - mu[r] * mu[r];
    inv[r] = rsqrtf(var + 1e-5f);
  }
#pragma unroll
  for (int c6 = 0; c6 < 6; ++c6){
    int ct = w * 6 + c6;
    int col = ct * 16 + (l & 15);
    float g = ln_g[col], bt = ln_b[col];
#pragma unroll
    for (int r = 0; r < 4; ++r)
      out[(long)(m0 + rb + r) * 384 + col] = (xa[c6][r] - mu[r]) * inv[r] * g + bt;
  }
}

// -------------------------------------------------------------------- launcher
extern "C" void kernel_launch(void* const* d_in, const int* in_sizes, int n_in,
                              void* d_out, int out_size, void* d_ws, size_t ws_size,
                              hipStream_t stream)
{
  const float* single = (const float*)d_in[0];
  const float* pair   = (const float*)d_in[1];
  const float* rot    = (const float*)d_in[2];
  const float* trans  = (const float*)d_in[3];
  const float* mask   = (const float*)d_in[4];
  const float* Wq  = (const float*)d_in[5];  const float* bq  = (const float*)d_in[6];
  const float* Wk  = (const float*)d_in[7];  const float* bk  = (const float*)d_in[8];
  const float* Wv  = (const float*)d_in[9];  const float* bv  = (const float*)d_in[10];
  const float* Wpb = (const float*)d_in[11]; const float* bpb = (const float*)d_in[12];
  const float* Wqp = (const float*)d_in[13]; const float* bqp = (const float*)d_in[14];
  const float* Wkp = (const float*)d_in[15]; const float* bkp = (const float*)d_in[16];
  const float* Wvp = (const float*)d_in[17]; const float* bvp = (const float*)d_in[18];
  const float* Wo  = (const float*)d_in[19]; const float* bo  = (const float*)d_in[20];
  const float* Wpo = (const float*)d_in[21]; const float* bpo = (const float*)d_in[22];
  const float* ln_g = (const float*)d_in[23]; const float* ln_b = (const float*)d_in[24];

  char* wsb = (char*)d_ws;
  size_t off = 0;
  auto alloc = [&](size_t bytes) -> void* {
    void* p = wsb + off; off += (bytes + 255) & ~(size_t)255; return p;
  };
  unsigned short* sbf  = (unsigned short*)alloc((size_t)BN * Cc * 2);
  unsigned short* wcat = (unsigned short*)alloc((size_t)12 * CT1 * 512 * 2);
  unsigned short* wpof = (unsigned short*)alloc((size_t)5 * 24 * 512 * 2);
  unsigned short* wof  = (unsigned short*)alloc((size_t)12 * 24 * 512 * 2);
  float* bcat  = (float*)alloc(NC1 * 4);
  float* proj  = (float*)alloc((size_t)BN * NC1 * 4);
  unsigned short* biasf = (unsigned short*)alloc((size_t)Bb * Hh * Nn * Nn * 2);
  unsigned short* qfragb = (unsigned short*)alloc((size_t)786432 * 2);
  unsigned short* kfragb = (unsigned short*)alloc((size_t)786432 * 2);
  unsigned short* vfragb = (unsigned short*)alloc((size_t)589824 * 2);
  float* q2hb  = (float*)alloc((size_t)12288 * 4);
  float* k2hb  = (float*)alloc((size_t)12288 * 4);
  float* wso   = (float*)alloc((size_t)BN * 384 * 4);
  unsigned short* wpbuf = (unsigned short*)alloc((size_t)BN * 160 * 2);
  if (off > ws_size) return;

  PrepArgs pa;
  pa.single = single; pa.Wq = Wq; pa.Wk = Wk; pa.Wv = Wv;
  pa.Wqp = Wqp; pa.Wkp = Wkp; pa.Wvp = Wvp;
  pa.bq = bq; pa.bk = bk; pa.bv = bv; pa.bqp = bqp; pa.bkp = bkp; pa.bvp = bvp;
  pa.sbf = sbf; pa.wcat = wcat; pa.bcat = bcat;

  prep_kernel<<<512, 256, 0, stream>>>(pa);
  gemm_mfma<<<dim3(16, 33), 256, 0, stream>>>(sbf, Cc, 12, wcat, CT1, bcat, proj, NC1);
  megapack_kernel<<<MEGA_GRID, 256, 0, stream>>>(
      pair, Wpb, bpb, proj, rot, trans, mask, Wpo, Wo,
      biasf, qfragb, kfragb, vfragb, q2hb, k2hb, wpof, wof, wpbuf);
  attn2_kernel<<<dim3(32, 12, 2), 256, 0, stream>>>(qfragb, kfragb, vfragb, biasf,
                                                    q2hb, k2hb, wso, wpbuf);
  tail_kernel<<<64, 256, 0, stream>>>(wpbuf, wpof, bpo, wso, wof, bo,
                                      single, ln_g, ln_b, (float*)d_out);
}